// Round 1
// baseline (2667.553 us; speedup 1.0000x reference)
//
#include <hip/hip_runtime.h>

// ---------------------------------------------------------------------------
// PWC-Net decoder level (B=16, C=48, H=64, W=128)
// Output layout: d_out = [flow 16*2*64*128][feat_out 16*269*64*128] (f32)
// feat_out channels: [c4 0..15][c3 16..39][c2 40..87][c1 88..135]
//                    [corr 136..216][feat1 217..264][upflow 265..266][upfeat 267..268]
// Every stage writes directly into d_out's feat region; convN reads the
// channel suffix [IN_OFF..268]. Scratch d_ws holds warped feat_2 (25.2 MB).
// ---------------------------------------------------------------------------

#define DEVFN __device__ __forceinline__

constexpr int B = 16, H = 64, W = 128, HW = H * W;     // 8192
constexpr int CF = 48;                                  // feat channels
constexpr int PFC = 217;                                // prev_feat channels
constexpr int H2 = 32, W2 = 64, HW2 = H2 * W2;          // 2048
constexpr int FC = 269;                                 // feat_out channels
constexpr int FLOW_ELEMS = B * 2 * HW;                  // 262144

constexpr int OFF_CORR = 136, OFF_F1 = 217, OFF_UF = 265, OFF_UPFEAT = 267;

DEVFN float leaky(float x) { return x >= 0.f ? x : 0.1f * x; }

// ------------------------- deconv4x4 s2 on prev_flow -----------------------
__global__ void k_deconv_flow(const float* __restrict__ pflow,
                              const float* __restrict__ wuf,
                              const float* __restrict__ buf_,
                              float* __restrict__ feat) {
  int t = blockIdx.x * blockDim.x + threadIdx.x;
  if (t >= B * 2 * HW) return;
  int x = t % W, y = (t / W) % H, co = (t / HW) % 2, b = t / (2 * HW);
  float acc = buf_[co];
  int ky0 = ((y & 1) == 0) ? 1 : 0;
  int kx0 = ((x & 1) == 0) ? 1 : 0;
#pragma unroll
  for (int kyi = 0; kyi < 2; ++kyi) {
    int ky = ky0 + 2 * kyi;
    int iy = (y + 1 - ky) >> 1;
    if (iy < 0 || iy >= H2) continue;
#pragma unroll
    for (int kxi = 0; kxi < 2; ++kxi) {
      int kx = kx0 + 2 * kxi;
      int ix = (x + 1 - kx) >> 1;
      if (ix < 0 || ix >= W2) continue;
#pragma unroll
      for (int ci = 0; ci < 2; ++ci)
        acc += pflow[(b * 2 + ci) * HW2 + iy * W2 + ix] *
               wuf[((ci * 2 + co) * 4 + ky) * 4 + kx];
    }
  }
  feat[(b * FC + OFF_UF + co) * HW + y * W + x] = acc;
}

// ------------------------- deconv4x4 s2 on prev_feat -----------------------
// thread = (b, y2, x2): computes 2x2 output block for both co. ky = 1+ry-2*dy.
__global__ __launch_bounds__(256) void k_deconv_feat(
    const float* __restrict__ pfeat, const float* __restrict__ wup,
    const float* __restrict__ bup, float* __restrict__ feat) {
  __shared__ float wl[PFC * 32];  // [ci][co][ky][kx] = 27776 B
  for (int i = threadIdx.x; i < PFC * 32; i += 256) wl[i] = wup[i];
  __syncthreads();
  int t = blockIdx.x * 256 + threadIdx.x;
  if (t >= B * HW2) return;
  int x2 = t % W2, y2 = (t / W2) % H2, b = t / HW2;
  float acc[2][2][2];
#pragma unroll
  for (int co = 0; co < 2; ++co) {
    float bv = bup[co];
#pragma unroll
    for (int ry = 0; ry < 2; ++ry)
#pragma unroll
      for (int rx = 0; rx < 2; ++rx) acc[co][ry][rx] = bv;
  }
  const float* src = pfeat + b * PFC * HW2;
#pragma unroll 1
  for (int ci = 0; ci < PFC; ++ci) {
    float iv[3][3];
#pragma unroll
    for (int dy = -1; dy <= 1; ++dy)
#pragma unroll
      for (int dx = -1; dx <= 1; ++dx) {
        int iy = y2 + dy, ix = x2 + dx;
        float v = 0.f;
        if (iy >= 0 && iy < H2 && ix >= 0 && ix < W2)
          v = src[ci * HW2 + iy * W2 + ix];
        iv[dy + 1][dx + 1] = v;
      }
    const float* wc = &wl[ci * 32];
#pragma unroll
    for (int co = 0; co < 2; ++co)
#pragma unroll
      for (int ry = 0; ry < 2; ++ry)
#pragma unroll
        for (int rx = 0; rx < 2; ++rx) {
          float s = acc[co][ry][rx];
#pragma unroll
          for (int dy = ry - 1; dy <= ry; ++dy) {
            int ky = 1 + ry - 2 * dy;
#pragma unroll
            for (int dx = rx - 1; dx <= rx; ++dx) {
              int kx = 1 + rx - 2 * dx;
              s += iv[dy + 1][dx + 1] * wc[co * 16 + ky * 4 + kx];
            }
          }
          acc[co][ry][rx] = s;
        }
  }
#pragma unroll
  for (int co = 0; co < 2; ++co)
#pragma unroll
    for (int ry = 0; ry < 2; ++ry)
#pragma unroll
      for (int rx = 0; rx < 2; ++rx)
        feat[(b * FC + OFF_UPFEAT + co) * HW + (2 * y2 + ry) * W + (2 * x2 + rx)] =
            acc[co][ry][rx];
}

// ------------------------------- backwarp ----------------------------------
// sample pos = x + flow_x * 1.25 * W/(W-1)  (align_corners=False algebra)
__global__ void k_backwarp(const float* __restrict__ feat2,
                           const float* __restrict__ feat,
                           float* __restrict__ warped) {
  int t = blockIdx.x * blockDim.x + threadIdx.x;
  if (t >= B * HW) return;
  int x = t % W, y = (t / W) % H, b = t / HW;
  const float SX = 1.25f * (float)W / (float)(W - 1);
  const float SY = 1.25f * (float)H / (float)(H - 1);
  float fx = feat[(b * FC + OFF_UF + 0) * HW + y * W + x];
  float fy = feat[(b * FC + OFF_UF + 1) * HW + y * W + x];
  float px = (float)x + fx * SX;
  float py = (float)y + fy * SY;
  float x0f = floorf(px), y0f = floorf(py);
  int ix0 = (int)x0f, iy0 = (int)y0f;
  float wx1 = px - x0f, wx0 = 1.f - wx1;
  float wy1 = py - y0f, wy0 = 1.f - wy1;
  bool vx0 = (ix0 >= 0) & (ix0 < W), vx1 = (ix0 + 1 >= 0) & (ix0 + 1 < W);
  bool vy0 = (iy0 >= 0) & (iy0 < H), vy1 = (iy0 + 1 >= 0) & (iy0 + 1 < H);
  float w00 = (vx0 && vy0) ? wx0 * wy0 : 0.f;
  float w01 = (vx1 && vy0) ? wx1 * wy0 : 0.f;
  float w10 = (vx0 && vy1) ? wx0 * wy1 : 0.f;
  float w11 = (vx1 && vy1) ? wx1 * wy1 : 0.f;
  float wsum = w00 + w01 + w10 + w11;
  float m = wsum > 0.999f ? 1.f : 0.f;
  w00 *= m; w01 *= m; w10 *= m; w11 *= m;
  int cx0 = min(max(ix0, 0), W - 1), cx1 = min(max(ix0 + 1, 0), W - 1);
  int cy0 = min(max(iy0, 0), H - 1), cy1 = min(max(iy0 + 1, 0), H - 1);
  const float* s = feat2 + b * CF * HW;
  int o00 = cy0 * W + cx0, o01 = cy0 * W + cx1, o10 = cy1 * W + cx0, o11 = cy1 * W + cx1;
#pragma unroll 1
  for (int c = 0; c < CF; ++c) {
    const float* sc = s + c * HW;
    float v = w00 * sc[o00] + w01 * sc[o01] + w10 * sc[o10] + w11 * sc[o11];
    warped[(b * CF + c) * HW + y * W + x] = v;
  }
}

// --------------------------- correlation + leaky ---------------------------
// block = one (b,y) row, 128 threads (one per x); 81 accumulators per thread.
// LDS tile: 8 channels x 9 rows x 136 cols of warped. Also copies feat_1 into
// feat channels 217..264 for free.
__global__ __launch_bounds__(128) void k_corr(const float* __restrict__ f1,
                                              const float* __restrict__ warped,
                                              float* __restrict__ feat) {
  __shared__ float tile[8][9][136];
  int x = threadIdx.x;
  int y = blockIdx.x % H, b = blockIdx.x / H;
  float acc[81];
#pragma unroll
  for (int d = 0; d < 81; ++d) acc[d] = 0.f;
#pragma unroll 1
  for (int c0 = 0; c0 < CF; c0 += 8) {
    __syncthreads();
    for (int i = threadIdx.x; i < 8 * 9 * 136; i += 128) {
      int cc = i / (9 * 136);
      int rem = i - cc * (9 * 136);
      int r = rem / 136, col = rem - r * 136;
      int yy = y + r - 4, xx = col - 4;
      float v = 0.f;
      if (yy >= 0 && yy < H && xx >= 0 && xx < W)
        v = warped[(b * CF + c0 + cc) * HW + yy * W + xx];
      tile[cc][r][col] = v;
    }
    __syncthreads();
#pragma unroll
    for (int cc = 0; cc < 8; ++cc) {
      float f1c = f1[(b * CF + c0 + cc) * HW + y * W + x];
      feat[(b * FC + OFF_F1 + c0 + cc) * HW + y * W + x] = f1c;  // free copy
#pragma unroll
      for (int dy = 0; dy < 9; ++dy) {
        const float* rp = &tile[cc][dy][x];
#pragma unroll
        for (int dx = 0; dx < 9; ++dx) acc[dy * 9 + dx] += f1c * rp[dx];
      }
    }
  }
  const float inv = 1.f / 48.f;
#pragma unroll
  for (int d = 0; d < 81; ++d)
    feat[(b * FC + OFF_CORR + d) * HW + y * W + x] = leaky(acc[d] * inv);
}

// ------------------------------ conv3x3 + leaky ----------------------------
// block = one (b,y) row. Threads: (128/P) x-groups x (COUT/CO_PT) co-groups.
// LDS: input chunk [8][3 rows][132 cols] + weights [8][COUT][12 (9 padded)].
template <int CIN, int COUT, int CO_PT, int P, int IN_OFF, int OUT_OFF, bool TO_FLOW>
__global__ __launch_bounds__((128 / P) * (COUT / CO_PT)) void k_conv(
    const float* __restrict__ src_feat, const float* __restrict__ wgt,
    const float* __restrict__ bias, float* __restrict__ dst_base) {
  constexpr int XG = 128 / P;
  constexpr int COG = COUT / CO_PT;
  constexpr int NT = XG * COG;
  constexpr int CC = 8;
  __shared__ float ls_in[CC][3][132];
  __shared__ float ls_w[CC][COUT][12];
  int y = blockIdx.x % H, b = blockIdx.x / H;
  int xg = threadIdx.x % XG, cog = threadIdx.x / XG;
  int x0 = xg * P;
  float acc[CO_PT][P];
#pragma unroll
  for (int cs = 0; cs < CO_PT; ++cs) {
    float bv = bias[cog * CO_PT + cs];
#pragma unroll
    for (int p = 0; p < P; ++p) acc[cs][p] = bv;
  }
  const float* srcb = src_feat + (b * FC + IN_OFF) * HW;
#pragma unroll 1
  for (int ci0 = 0; ci0 < CIN; ci0 += CC) {
    int nch = (CIN - ci0 < CC) ? (CIN - ci0) : CC;
    __syncthreads();
    for (int i = threadIdx.x; i < nch * 3 * 130; i += NT) {
      int cc = i / 390;
      int rem = i - cc * 390;
      int r = rem / 130, col = rem - r * 130;
      int yy = y + r - 1, xx = col - 1;
      float v = 0.f;
      if (yy >= 0 && yy < H && xx >= 0 && xx < W)
        v = srcb[(ci0 + cc) * HW + yy * W + xx];
      ls_in[cc][r][col] = v;
    }
    for (int i = threadIdx.x; i < nch * COUT * 9; i += NT) {
      int cc = i / (COUT * 9);
      int rem = i - cc * (COUT * 9);
      int co = rem / 9, tt = rem - co * 9;
      ls_w[cc][co][tt] = wgt[(co * CIN + ci0 + cc) * 9 + tt];
    }
    __syncthreads();
#pragma unroll 1
    for (int ci = 0; ci < nch; ++ci) {
      float iv[3][P + 2];
#pragma unroll
      for (int r = 0; r < 3; ++r)
#pragma unroll
        for (int c = 0; c < P + 2; ++c) iv[r][c] = ls_in[ci][r][x0 + c];
#pragma unroll
      for (int cs = 0; cs < CO_PT; ++cs) {
        int co = cog * CO_PT + cs;
        float w9[9];
#pragma unroll
        for (int tt = 0; tt < 9; ++tt) w9[tt] = ls_w[ci][co][tt];
#pragma unroll
        for (int p = 0; p < P; ++p) {
          float s = acc[cs][p];
#pragma unroll
          for (int r = 0; r < 3; ++r)
#pragma unroll
            for (int tt = 0; tt < 3; ++tt) s += iv[r][p + tt] * w9[r * 3 + tt];
          acc[cs][p] = s;
        }
      }
    }
  }
#pragma unroll
  for (int cs = 0; cs < CO_PT; ++cs) {
    int co = cog * CO_PT + cs;
    int chan = TO_FLOW ? (b * 2 + co) : (b * FC + OUT_OFF + co);
    float* dp = dst_base + chan * HW + y * W + x0;
#pragma unroll
    for (int p = 0; p < P; ++p) dp[p] = leaky(acc[cs][p]);
  }
}

// ---------------------------------------------------------------------------
extern "C" void kernel_launch(void* const* d_in, const int* in_sizes, int n_in,
                              void* d_out, int out_size, void* d_ws, size_t ws_size,
                              hipStream_t stream) {
  (void)in_sizes; (void)n_in; (void)out_size; (void)ws_size;
  const float* feat_1 = (const float*)d_in[0];
  const float* feat_2 = (const float*)d_in[1];
  const float* prev_flow = (const float*)d_in[2];
  const float* prev_feat = (const float*)d_in[3];
  const float* w1 = (const float*)d_in[4];
  const float* b1 = (const float*)d_in[5];
  const float* w2 = (const float*)d_in[6];
  const float* b2 = (const float*)d_in[7];
  const float* w3 = (const float*)d_in[8];
  const float* b3 = (const float*)d_in[9];
  const float* w4 = (const float*)d_in[10];
  const float* b4 = (const float*)d_in[11];
  const float* w5 = (const float*)d_in[12];
  const float* b5 = (const float*)d_in[13];
  const float* w_upflow = (const float*)d_in[14];
  const float* b_upflow = (const float*)d_in[15];
  const float* w_upfeat = (const float*)d_in[16];
  const float* b_upfeat = (const float*)d_in[17];

  float* out = (float*)d_out;
  float* feat = out + FLOW_ELEMS;          // feat_out region
  float* warped = (float*)d_ws;            // 16*48*8192 f32 = 25.2 MB

  k_deconv_flow<<<(B * 2 * HW) / 256, 256, 0, stream>>>(prev_flow, w_upflow, b_upflow, feat);
  k_deconv_feat<<<(B * HW2) / 256, 256, 0, stream>>>(prev_feat, w_upfeat, b_upfeat, feat);
  k_backwarp<<<(B * HW) / 256, 256, 0, stream>>>(feat_2, feat, warped);
  k_corr<<<B * H, 128, 0, stream>>>(feat_1, warped, feat);

  k_conv<133, 48, 6, 4, 136, 88, false><<<B * H, 256, 0, stream>>>(feat, w1, b1, feat);
  k_conv<181, 48, 6, 4, 88, 40, false><<<B * H, 256, 0, stream>>>(feat, w2, b2, feat);
  k_conv<229, 24, 3, 4, 40, 16, false><<<B * H, 256, 0, stream>>>(feat, w3, b3, feat);
  k_conv<253, 16, 2, 4, 16, 0, false><<<B * H, 256, 0, stream>>>(feat, w4, b4, feat);
  k_conv<269, 2, 2, 2, 0, 0, true><<<B * H, 64, 0, stream>>>(feat, w5, b5, out);
}

// Round 2
// 940.615 us; speedup vs baseline: 2.8360x; 2.8360x over previous
//
#include <hip/hip_runtime.h>

// ---------------------------------------------------------------------------
// PWC-Net decoder level (B=16, C=48, H=64, W=128) — MFMA implicit-GEMM convs.
// d_out = [flow 16*2*64*128][feat_out 16*269*64*128] (f32)
// feat_out channels: [c4 0..15][c3 16..39][c2 40..87][c1 88..135]
//                    [corr 136..216][feat1 217..264][upflow 265..266][upfeat 267..268]
// d_ws: [zeros 64B][featb: bf16 channel-last [B][H][W][272], ch 269..271 = 0]
//       [warped f32 25MB][wb1..wb5: repacked bf16 swizzled weights]
// ---------------------------------------------------------------------------

#define DEVFN __device__ __forceinline__

constexpr int B = 16, H = 64, W = 128, HW = H * W;
constexpr int CF = 48;
constexpr int PFC = 217;
constexpr int H2 = 32, W2 = 64, HW2 = H2 * W2;
constexpr int FC = 269;
constexpr int FCP = 272;                 // padded channel-last stride
constexpr int FLOW_ELEMS = B * 2 * HW;

constexpr int OFF_CORR = 136, OFF_F1 = 217, OFF_UF = 265, OFF_UPFEAT = 267;

// ws layout (bytes)
constexpr size_t WS_ZEROS = 0;
constexpr size_t WS_FEATB = 256;
constexpr size_t FEATB_BYTES = (size_t)B * HW * FCP * 2;     // 71,303,168
constexpr size_t WS_WARPED = WS_FEATB + FEATB_BYTES;
constexpr size_t WARPED_BYTES = (size_t)B * CF * HW * 4;     // 25,165,824
constexpr size_t WS_WB = WS_WARPED + WARPED_BYTES;

typedef short bf16x8 __attribute__((ext_vector_type(8)));
typedef float f32x4 __attribute__((ext_vector_type(4)));

DEVFN float leaky(float x) { return x >= 0.f ? x : 0.1f * x; }

DEVFN unsigned short f2b(float f) {  // RNE f32 -> bf16
  unsigned int u = __float_as_uint(f);
  u += 0x7FFFu + ((u >> 16) & 1u);
  return (unsigned short)(u >> 16);
}

DEVFN void gload16(const void* g, void* l) {
  __builtin_amdgcn_global_load_lds(
      (const __attribute__((address_space(1))) void*)g,
      (__attribute__((address_space(3))) void*)l, 16, 0, 0);
}

// ------------------------- deconv4x4 s2 on prev_flow -----------------------
__global__ void k_deconv_flow(const float* __restrict__ pflow,
                              const float* __restrict__ wuf,
                              const float* __restrict__ buf_,
                              float* __restrict__ feat,
                              unsigned short* __restrict__ featb) {
  int t = blockIdx.x * blockDim.x + threadIdx.x;
  if (t >= B * 2 * HW) return;
  int x = t % W, y = (t / W) % H, co = (t / HW) % 2, b = t / (2 * HW);
  float acc = buf_[co];
  int ky0 = ((y & 1) == 0) ? 1 : 0;
  int kx0 = ((x & 1) == 0) ? 1 : 0;
#pragma unroll
  for (int kyi = 0; kyi < 2; ++kyi) {
    int ky = ky0 + 2 * kyi;
    int iy = (y + 1 - ky) >> 1;
    if (iy < 0 || iy >= H2) continue;
#pragma unroll
    for (int kxi = 0; kxi < 2; ++kxi) {
      int kx = kx0 + 2 * kxi;
      int ix = (x + 1 - kx) >> 1;
      if (ix < 0 || ix >= W2) continue;
#pragma unroll
      for (int ci = 0; ci < 2; ++ci)
        acc += pflow[(b * 2 + ci) * HW2 + iy * W2 + ix] *
               wuf[((ci * 2 + co) * 4 + ky) * 4 + kx];
    }
  }
  int pix = (b * H + y) * W + x;
  feat[(b * FC + OFF_UF + co) * HW + y * W + x] = acc;
  featb[pix * FCP + OFF_UF + co] = f2b(acc);
  if (co == 0) {  // zero the bf16 channel pads once per pixel
    featb[pix * FCP + 269] = 0;
    featb[pix * FCP + 270] = 0;
    featb[pix * FCP + 271] = 0;
  }
}

// ------------------------- deconv4x4 s2 on prev_feat -----------------------
__global__ __launch_bounds__(256) void k_deconv_feat(
    const float* __restrict__ pfeat, const float* __restrict__ wup,
    const float* __restrict__ bup, float* __restrict__ feat,
    unsigned short* __restrict__ featb) {
  __shared__ float wl[PFC * 32];
  for (int i = threadIdx.x; i < PFC * 32; i += 256) wl[i] = wup[i];
  __syncthreads();
  int t = blockIdx.x * 256 + threadIdx.x;
  if (t >= B * HW2) return;
  int x2 = t % W2, y2 = (t / W2) % H2, b = t / HW2;
  float acc[2][2][2];
#pragma unroll
  for (int co = 0; co < 2; ++co) {
    float bv = bup[co];
#pragma unroll
    for (int ry = 0; ry < 2; ++ry)
#pragma unroll
      for (int rx = 0; rx < 2; ++rx) acc[co][ry][rx] = bv;
  }
  const float* src = pfeat + b * PFC * HW2;
#pragma unroll 1
  for (int ci = 0; ci < PFC; ++ci) {
    float iv[3][3];
#pragma unroll
    for (int dy = -1; dy <= 1; ++dy)
#pragma unroll
      for (int dx = -1; dx <= 1; ++dx) {
        int iy = y2 + dy, ix = x2 + dx;
        float v = 0.f;
        if (iy >= 0 && iy < H2 && ix >= 0 && ix < W2)
          v = src[ci * HW2 + iy * W2 + ix];
        iv[dy + 1][dx + 1] = v;
      }
    const float* wc = &wl[ci * 32];
#pragma unroll
    for (int co = 0; co < 2; ++co)
#pragma unroll
      for (int ry = 0; ry < 2; ++ry)
#pragma unroll
        for (int rx = 0; rx < 2; ++rx) {
          float s = acc[co][ry][rx];
#pragma unroll
          for (int dy = ry - 1; dy <= ry; ++dy) {
            int ky = 1 + ry - 2 * dy;
#pragma unroll
            for (int dx = rx - 1; dx <= rx; ++dx) {
              int kx = 1 + rx - 2 * dx;
              s += iv[dy + 1][dx + 1] * wc[co * 16 + ky * 4 + kx];
            }
          }
          acc[co][ry][rx] = s;
        }
  }
#pragma unroll
  for (int co = 0; co < 2; ++co)
#pragma unroll
    for (int ry = 0; ry < 2; ++ry)
#pragma unroll
      for (int rx = 0; rx < 2; ++rx) {
        int yy = 2 * y2 + ry, xx = 2 * x2 + rx;
        float v = acc[co][ry][rx];
        feat[(b * FC + OFF_UPFEAT + co) * HW + yy * W + xx] = v;
        featb[((b * H + yy) * W + xx) * FCP + OFF_UPFEAT + co] = f2b(v);
      }
}

// ------------------------------- backwarp ----------------------------------
__global__ void k_backwarp(const float* __restrict__ feat2,
                           const float* __restrict__ feat,
                           float* __restrict__ warped) {
  int t = blockIdx.x * blockDim.x + threadIdx.x;
  if (t >= B * HW) return;
  int x = t % W, y = (t / W) % H, b = t / HW;
  const float SX = 1.25f * (float)W / (float)(W - 1);
  const float SY = 1.25f * (float)H / (float)(H - 1);
  float fx = feat[(b * FC + OFF_UF + 0) * HW + y * W + x];
  float fy = feat[(b * FC + OFF_UF + 1) * HW + y * W + x];
  float px = (float)x + fx * SX;
  float py = (float)y + fy * SY;
  float x0f = floorf(px), y0f = floorf(py);
  int ix0 = (int)x0f, iy0 = (int)y0f;
  float wx1 = px - x0f, wx0 = 1.f - wx1;
  float wy1 = py - y0f, wy0 = 1.f - wy1;
  bool vx0 = (ix0 >= 0) & (ix0 < W), vx1 = (ix0 + 1 >= 0) & (ix0 + 1 < W);
  bool vy0 = (iy0 >= 0) & (iy0 < H), vy1 = (iy0 + 1 >= 0) & (iy0 + 1 < H);
  float w00 = (vx0 && vy0) ? wx0 * wy0 : 0.f;
  float w01 = (vx1 && vy0) ? wx1 * wy0 : 0.f;
  float w10 = (vx0 && vy1) ? wx0 * wy1 : 0.f;
  float w11 = (vx1 && vy1) ? wx1 * wy1 : 0.f;
  float wsum = w00 + w01 + w10 + w11;
  float m = wsum > 0.999f ? 1.f : 0.f;
  w00 *= m; w01 *= m; w10 *= m; w11 *= m;
  int cx0 = min(max(ix0, 0), W - 1), cx1 = min(max(ix0 + 1, 0), W - 1);
  int cy0 = min(max(iy0, 0), H - 1), cy1 = min(max(iy0 + 1, 0), H - 1);
  const float* s = feat2 + b * CF * HW;
  int o00 = cy0 * W + cx0, o01 = cy0 * W + cx1, o10 = cy1 * W + cx0, o11 = cy1 * W + cx1;
#pragma unroll 1
  for (int c = 0; c < CF; ++c) {
    const float* sc = s + c * HW;
    float v = w00 * sc[o00] + w01 * sc[o01] + w10 * sc[o10] + w11 * sc[o11];
    warped[(b * CF + c) * HW + y * W + x] = v;
  }
}

// --------------------------- correlation + leaky ---------------------------
__global__ __launch_bounds__(128) void k_corr(const float* __restrict__ f1,
                                              const float* __restrict__ warped,
                                              float* __restrict__ feat,
                                              unsigned short* __restrict__ featb) {
  __shared__ float tile[8][9][136];
  int x = threadIdx.x;
  int y = blockIdx.x % H, b = blockIdx.x / H;
  int pixF = ((b * H + y) * W + x) * FCP;
  float acc[81];
#pragma unroll
  for (int d = 0; d < 81; ++d) acc[d] = 0.f;
#pragma unroll 1
  for (int c0 = 0; c0 < CF; c0 += 8) {
    __syncthreads();
    for (int i = threadIdx.x; i < 8 * 9 * 136; i += 128) {
      int cc = i / (9 * 136);
      int rem = i - cc * (9 * 136);
      int r = rem / 136, col = rem - r * 136;
      int yy = y + r - 4, xx = col - 4;
      float v = 0.f;
      if (yy >= 0 && yy < H && xx >= 0 && xx < W)
        v = warped[(b * CF + c0 + cc) * HW + yy * W + xx];
      tile[cc][r][col] = v;
    }
    __syncthreads();
#pragma unroll
    for (int cc = 0; cc < 8; ++cc) {
      float f1c = f1[(b * CF + c0 + cc) * HW + y * W + x];
      feat[(b * FC + OFF_F1 + c0 + cc) * HW + y * W + x] = f1c;
      featb[pixF + OFF_F1 + c0 + cc] = f2b(f1c);
#pragma unroll
      for (int dy = 0; dy < 9; ++dy) {
        const float* rp = &tile[cc][dy][x];
#pragma unroll
        for (int dx = 0; dx < 9; ++dx) acc[dy * 9 + dx] += f1c * rp[dx];
      }
    }
  }
  const float inv = 1.f / 48.f;
#pragma unroll
  for (int d = 0; d < 81; ++d) {
    float v = leaky(acc[d] * inv);
    feat[(b * FC + OFF_CORR + d) * HW + y * W + x] = v;
    featb[pixF + OFF_CORR + d] = f2b(v);
  }
}

// ----------------- weight repack: f32 [co][ci][3][3] -> bf16 ---------------
// wb layout: [chunk][tap][co][qpos][j]  (32 ci per chunk, swizzle baked:
// position qpos holds channels (qpos ^ ((co>>1)&3))*8 + j). Zero-padded.
template <int CIN, int NCHUNK, int COUT, int COUTP>
__global__ void k_repack(const float* __restrict__ w, unsigned short* __restrict__ wb) {
  int e = blockIdx.x * 256 + threadIdx.x;
  constexpr int TOT = NCHUNK * 9 * COUTP * 32;
  if (e >= TOT) return;
  int j = e & 7, qpos = (e >> 3) & 3;
  int row = e >> 5;                 // (ch*9 + tap)*COUTP + co
  int co = row % COUTP;
  int tapch = row / COUTP;
  int tap = tapch % 9, ch = tapch / 9;
  int ci = ch * 32 + ((qpos ^ ((co >> 1) & 3)) << 3) + j;
  float v = 0.f;
  if (co < COUT && ci < CIN) v = w[(co * CIN + ci) * 9 + tap];
  wb[e] = f2b(v);
}

// --------------------- conv3x3 + bias + leaky via MFMA ---------------------
// Block = one (b,y) row: M=128 pixels. 4 waves; wave w -> M-frags {2w,2w+1}
// (16 px each), all NF N-frags. K = chunks of 32 channels x 9 taps.
// LDS: ls_in [3 rows][144 slots][32ch] bf16 (slot = x+1), ls_w [9][COUTP][32].
// Swizzle: 16B sub-slice q' = q ^ ((slot>>1)&3)  (input; applied at stage+read)
//          and q' = q ^ ((co>>1)&3)              (weights; baked in wb).
template <int CIN, int NCHUNK, int COUT, int COUTP, int IN_OFF, int OUT_OFF, bool TO_FLOW>
__global__ __launch_bounds__(256) void k_conv_mfma(
    const unsigned short* __restrict__ featb, const unsigned short* __restrict__ wb,
    const float* __restrict__ bias, const unsigned short* __restrict__ zeros,
    float* __restrict__ fout, unsigned short* __restrict__ bout) {
  constexpr int NF = COUTP / 16;
  constexpr int ROWPX = 144;
  constexpr int IN_ELE = 3 * ROWPX * 32;      // ushorts
  constexpr int W_SLAB = 9 * COUTP * 32;      // ushorts per chunk
  constexpr int NIN = 27;
  constexpr int NWI = (W_SLAB * 2) / 1024;
  constexpr int NINST = NIN + NWI;
  constexpr int MYI = (NINST + 3) / 4;
  constexpr int CLIM = 264 - IN_OFF;          // c8 <= CLIM reads real data

  __shared__ unsigned short lds[IN_ELE + W_SLAB];

  const int y = blockIdx.x % H, b = blockIdx.x / H;
  const int lane = threadIdx.x & 63, wv = threadIdx.x >> 6;
  const int arow = lane & 15, aslc = lane >> 4;

  // ---- precompute staging descriptors (unrolled -> registers) ----
  const unsigned short* gp[MYI];
  int c8a[MYI];
  int lofs[MYI];
  bool iw[MYI];
#pragma unroll
  for (int t = 0; t < MYI; ++t) {
    int i = wv + t * 4;
    gp[t] = zeros; c8a[t] = 1 << 20; lofs[t] = 0; iw[t] = false;
    if (i < NIN) {
      int r = i / 9, seg = i - r * 9;
      int slot = seg * 16 + (lane >> 2);
      int sub8 = ((lane & 3) ^ ((slot >> 1) & 3)) << 3;
      int yy = y + r - 1, xx = slot - 1;
      lofs[t] = (r * ROWPX + seg * 16) * 64;   // LDS byte offset
      if (yy >= 0 && yy < H && xx >= 0 && xx < W) {
        gp[t] = featb + ((b * H + yy) * W + xx) * FCP + IN_OFF + sub8;
        c8a[t] = sub8;
      }
    } else if (i < NINST) {
      int wi = i - NIN;
      iw[t] = true;
      gp[t] = wb + wi * 512 + lane * 8;
      lofs[t] = IN_ELE * 2 + wi * 1024;
    }
  }

  // ---- LDS read offsets (ushort units) ----
  int a_off[2][3];
#pragma unroll
  for (int mi = 0; mi < 2; ++mi)
#pragma unroll
    for (int kx = 0; kx < 3; ++kx) {
      int slot = (wv * 2 + mi) * 16 + arow + kx;
      a_off[mi][kx] = slot * 32 + ((aslc ^ ((slot >> 1) & 3)) << 3);
    }
  int b_off[NF];
#pragma unroll
  for (int nf = 0; nf < NF; ++nf) {
    int co = nf * 16 + arow;
    b_off[nf] = IN_ELE + co * 32 + ((aslc ^ ((co >> 1) & 3)) << 3);
  }

  f32x4 acc[2][NF];
#pragma unroll
  for (int mi = 0; mi < 2; ++mi)
#pragma unroll
    for (int nf = 0; nf < NF; ++nf) acc[mi][nf] = (f32x4){0.f, 0.f, 0.f, 0.f};

  char* ldsc = (char*)lds;

  for (int ch = 0; ch < NCHUNK; ++ch) {
    const int ci0 = ch * 32;
    __syncthreads();
#pragma unroll
    for (int t = 0; t < MYI; ++t) {
      int i = wv + t * 4;
      if (i < NINST) {
        const unsigned short* g;
        if (iw[t]) g = gp[t] + (size_t)ch * W_SLAB;
        else       g = (c8a[t] + ci0 <= CLIM) ? gp[t] + ci0 : zeros;
        gload16(g, ldsc + lofs[t]);
      }
    }
    asm volatile("s_waitcnt vmcnt(0)" ::: "memory");
    __syncthreads();
#pragma unroll
    for (int ky = 0; ky < 3; ++ky) {
#pragma unroll
      for (int kx = 0; kx < 3; ++kx) {
        bf16x8 afr[2];
#pragma unroll
        for (int mi = 0; mi < 2; ++mi)
          afr[mi] = *(const bf16x8*)(lds + a_off[mi][kx] + ky * (ROWPX * 32));
#pragma unroll
        for (int nf = 0; nf < NF; ++nf) {
          bf16x8 bfr = *(const bf16x8*)(lds + b_off[nf] + (ky * 3 + kx) * (COUTP * 32));
#pragma unroll
          for (int mi = 0; mi < 2; ++mi)
            acc[mi][nf] = __builtin_amdgcn_mfma_f32_16x16x32_bf16(
                afr[mi], bfr, acc[mi][nf], 0, 0, 0);
        }
      }
    }
  }

  // ---- epilogue: D row=(lane>>4)*4+r (pixel), col=lane&15 (co) ----
  const int dcol = lane & 15;
#pragma unroll
  for (int nf = 0; nf < NF; ++nf) {
    int co = nf * 16 + dcol;
    if (co < COUT) {
      float bv = bias[co];
#pragma unroll
      for (int mi = 0; mi < 2; ++mi) {
#pragma unroll
        for (int r = 0; r < 4; ++r) {
          int pixel = (wv * 2 + mi) * 16 + (lane >> 4) * 4 + r;
          float v = leaky(acc[mi][nf][r] + bv);
          if constexpr (TO_FLOW) {
            fout[(b * 2 + co) * HW + y * W + pixel] = v;
          } else {
            fout[(b * FC + OUT_OFF + co) * HW + y * W + pixel] = v;
            bout[((b * H + y) * W + pixel) * FCP + OUT_OFF + co] = f2b(v);
          }
        }
      }
    }
  }
}

// ---------------------------------------------------------------------------
extern "C" void kernel_launch(void* const* d_in, const int* in_sizes, int n_in,
                              void* d_out, int out_size, void* d_ws, size_t ws_size,
                              hipStream_t stream) {
  (void)in_sizes; (void)n_in; (void)out_size; (void)ws_size;
  const float* feat_1 = (const float*)d_in[0];
  const float* feat_2 = (const float*)d_in[1];
  const float* prev_flow = (const float*)d_in[2];
  const float* prev_feat = (const float*)d_in[3];
  const float* w1 = (const float*)d_in[4];
  const float* b1 = (const float*)d_in[5];
  const float* w2 = (const float*)d_in[6];
  const float* b2 = (const float*)d_in[7];
  const float* w3 = (const float*)d_in[8];
  const float* b3 = (const float*)d_in[9];
  const float* w4 = (const float*)d_in[10];
  const float* b4 = (const float*)d_in[11];
  const float* w5 = (const float*)d_in[12];
  const float* b5 = (const float*)d_in[13];
  const float* w_upflow = (const float*)d_in[14];
  const float* b_upflow = (const float*)d_in[15];
  const float* w_upfeat = (const float*)d_in[16];
  const float* b_upfeat = (const float*)d_in[17];

  float* out = (float*)d_out;
  float* feat = out + FLOW_ELEMS;

  char* ws = (char*)d_ws;
  unsigned short* zeros = (unsigned short*)(ws + WS_ZEROS);
  unsigned short* featb = (unsigned short*)(ws + WS_FEATB);
  float* warped = (float*)(ws + WS_WARPED);
  unsigned short* wb1 = (unsigned short*)(ws + WS_WB);
  unsigned short* wb2 = wb1 + 5 * 9 * 48 * 32;
  unsigned short* wb3 = wb2 + 6 * 9 * 48 * 32;
  unsigned short* wb4 = wb3 + 8 * 9 * 32 * 32;
  unsigned short* wb5 = wb4 + 8 * 9 * 16 * 32;

  hipMemsetAsync(zeros, 0, 64, stream);

  k_repack<133, 5, 48, 48><<<270, 256, 0, stream>>>(w1, wb1);
  k_repack<181, 6, 48, 48><<<324, 256, 0, stream>>>(w2, wb2);
  k_repack<229, 8, 24, 32><<<288, 256, 0, stream>>>(w3, wb3);
  k_repack<253, 8, 16, 16><<<144, 256, 0, stream>>>(w4, wb4);
  k_repack<269, 9, 2, 16><<<162, 256, 0, stream>>>(w5, wb5);

  k_deconv_flow<<<(B * 2 * HW) / 256, 256, 0, stream>>>(prev_flow, w_upflow, b_upflow, feat, featb);
  k_deconv_feat<<<(B * HW2) / 256, 256, 0, stream>>>(prev_feat, w_upfeat, b_upfeat, feat, featb);
  k_backwarp<<<(B * HW) / 256, 256, 0, stream>>>(feat_2, feat, warped);
  k_corr<<<B * H, 128, 0, stream>>>(feat_1, warped, feat, featb);

  k_conv_mfma<133, 5, 48, 48, 136, 88, false><<<B * H, 256, 0, stream>>>(featb, wb1, b1, zeros, feat, featb);
  k_conv_mfma<181, 6, 48, 48, 88, 40, false><<<B * H, 256, 0, stream>>>(featb, wb2, b2, zeros, feat, featb);
  k_conv_mfma<229, 8, 24, 32, 40, 16, false><<<B * H, 256, 0, stream>>>(featb, wb3, b3, zeros, feat, featb);
  k_conv_mfma<253, 8, 16, 16, 16, 0, false><<<B * H, 256, 0, stream>>>(featb, wb4, b4, zeros, feat, featb);
  k_conv_mfma<269, 9, 2, 16, 0, 0, true><<<B * H, 256, 0, stream>>>(featb, wb5, b5, zeros, out, nullptr);
}

// Round 3
// 476.988 us; speedup vs baseline: 5.5925x; 1.9720x over previous
//
#include <hip/hip_runtime.h>

// ---------------------------------------------------------------------------
// PWC-Net decoder level (B=16, C=48, H=64, W=128) — MFMA implicit-GEMM convs.
// d_out = [flow 16*2*64*128][feat_out 16*269*64*128] (f32)
// feat_out channels: [c4 0..15][c3 16..39][c2 40..87][c1 88..135]
//                    [corr 136..216][feat1 217..264][upflow 265..266][upfeat 267..268]
// d_ws: [zeros 64B][featb bf16 [B][H][W][272]][warpedh fp16 [3][B*HW][16]]
//       [partial f32 [7][B*2*HW]][wb1..wb5 repacked bf16 weights]
// ---------------------------------------------------------------------------

#define DEVFN __device__ __forceinline__

constexpr int B = 16, H = 64, W = 128, HW = H * W;
constexpr int CF = 48;
constexpr int PFC = 217;
constexpr int H2 = 32, W2 = 64, HW2 = H2 * W2;
constexpr int FC = 269;
constexpr int FCP = 272;
constexpr int FLOW_ELEMS = B * 2 * HW;

constexpr int OFF_CORR = 136, OFF_F1 = 217, OFF_UF = 265, OFF_UPFEAT = 267;

// ws layout (bytes)
constexpr size_t WS_ZEROS = 0;
constexpr size_t WS_FEATB = 256;
constexpr size_t FEATB_BYTES = (size_t)B * HW * FCP * 2;      // 71,303,168
constexpr size_t WS_WARPEDH = WS_FEATB + FEATB_BYTES;
constexpr size_t WARPEDH_BYTES = (size_t)3 * B * HW * 16 * 2; // 12,582,912
constexpr size_t WS_PART = WS_WARPEDH + WARPEDH_BYTES;
constexpr size_t PART_BYTES = (size_t)7 * B * 2 * HW * 4;     // 7,340,032
constexpr size_t WS_WB = WS_PART + PART_BYTES;

typedef short bf16x8 __attribute__((ext_vector_type(8)));
typedef float f32x4 __attribute__((ext_vector_type(4)));
typedef _Float16 h16x2 __attribute__((ext_vector_type(2)));
typedef _Float16 h16x8 __attribute__((ext_vector_type(8)));

DEVFN float leaky(float x) { return x >= 0.f ? x : 0.1f * x; }

DEVFN unsigned short f2b(float f) {  // RNE f32 -> bf16
  unsigned int u = __float_as_uint(f);
  u += 0x7FFFu + ((u >> 16) & 1u);
  return (unsigned short)(u >> 16);
}

DEVFN void gload16(const void* g, void* l) {
  __builtin_amdgcn_global_load_lds(
      (const __attribute__((address_space(1))) void*)g,
      (__attribute__((address_space(3))) void*)l, 16, 0, 0);
}

// ------------------------- deconv4x4 s2 on prev_flow -----------------------
__global__ void k_deconv_flow(const float* __restrict__ pflow,
                              const float* __restrict__ wuf,
                              const float* __restrict__ buf_,
                              float* __restrict__ feat,
                              unsigned short* __restrict__ featb) {
  int t = blockIdx.x * blockDim.x + threadIdx.x;
  if (t >= B * 2 * HW) return;
  int x = t % W, y = (t / W) % H, co = (t / HW) % 2, b = t / (2 * HW);
  float acc = buf_[co];
  int ky0 = ((y & 1) == 0) ? 1 : 0;
  int kx0 = ((x & 1) == 0) ? 1 : 0;
#pragma unroll
  for (int kyi = 0; kyi < 2; ++kyi) {
    int ky = ky0 + 2 * kyi;
    int iy = (y + 1 - ky) >> 1;
    if (iy < 0 || iy >= H2) continue;
#pragma unroll
    for (int kxi = 0; kxi < 2; ++kxi) {
      int kx = kx0 + 2 * kxi;
      int ix = (x + 1 - kx) >> 1;
      if (ix < 0 || ix >= W2) continue;
#pragma unroll
      for (int ci = 0; ci < 2; ++ci)
        acc += pflow[(b * 2 + ci) * HW2 + iy * W2 + ix] *
               wuf[((ci * 2 + co) * 4 + ky) * 4 + kx];
    }
  }
  int pix = (b * H + y) * W + x;
  feat[(b * FC + OFF_UF + co) * HW + y * W + x] = acc;
  featb[pix * FCP + OFF_UF + co] = f2b(acc);
  if (co == 0) {
    featb[pix * FCP + 269] = 0;
    featb[pix * FCP + 270] = 0;
    featb[pix * FCP + 271] = 0;
  }
}

// ----------------- deconv4x4 s2 on prev_feat: partial pass -----------------
// grid = B*H2*7; block handles (b,y2) x 32-ch chunk; 256 thr = 64 px x 4 cgrp.
__global__ __launch_bounds__(256) void k_dcf_part(
    const float* __restrict__ pfeat, const float* __restrict__ wup,
    float* __restrict__ partial) {
  __shared__ float wl[1024];   // [ci_local][co*16+ky*4+kx]
  __shared__ float red[2048];  // [cg][x2][8]
  int blk = blockIdx.x;
  int chunk = blk % 7, t2 = blk / 7;
  int y2 = t2 % H2, b = t2 / H2;
  int tid = threadIdx.x;
  int ch0 = chunk * 32;
  for (int i = tid; i < 1024; i += 256) {
    int ci = ch0 + (i >> 5);
    wl[i] = (ci < PFC) ? wup[ci * 32 + (i & 31)] : 0.f;
  }
  __syncthreads();
  int x2 = tid & 63, cg = tid >> 6;
  float acc[8];
#pragma unroll
  for (int v = 0; v < 8; ++v) acc[v] = 0.f;
#pragma unroll 1
  for (int k = 0; k < 8; ++k) {
    int cil = cg * 8 + k;
    int ci = ch0 + cil;
    bool cv = ci < PFC;
    const float* src = pfeat + ((size_t)b * PFC + ci) * HW2;
    float iv[3][3];
#pragma unroll
    for (int dy = -1; dy <= 1; ++dy)
#pragma unroll
      for (int dx = -1; dx <= 1; ++dx) {
        int iy = y2 + dy, ix = x2 + dx;
        float v = 0.f;
        if (cv && iy >= 0 && iy < H2 && ix >= 0 && ix < W2) v = src[iy * W2 + ix];
        iv[dy + 1][dx + 1] = v;
      }
    const float* wc = &wl[cil * 32];
#pragma unroll
    for (int co = 0; co < 2; ++co)
#pragma unroll
      for (int ry = 0; ry < 2; ++ry)
#pragma unroll
        for (int rx = 0; rx < 2; ++rx) {
          float s = acc[co * 4 + ry * 2 + rx];
#pragma unroll
          for (int dy = ry - 1; dy <= ry; ++dy) {
            int ky = 1 + ry - 2 * dy;
#pragma unroll
            for (int dx = rx - 1; dx <= rx; ++dx) {
              int kx = 1 + rx - 2 * dx;
              s += iv[dy + 1][dx + 1] * wc[co * 16 + ky * 4 + kx];
            }
          }
          acc[co * 4 + ry * 2 + rx] = s;
        }
  }
#pragma unroll
  for (int v = 0; v < 8; ++v) red[(cg * 64 + x2) * 8 + v] = acc[v];
  __syncthreads();
  for (int idx = tid; idx < 512; idx += 256) {
    int x2b = idx & 63, vi = idx >> 6;
    float s = red[(0 + x2b) * 8 + vi] + red[(64 + x2b) * 8 + vi] +
              red[(128 + x2b) * 8 + vi] + red[(192 + x2b) * 8 + vi];
    int co = vi >> 2, ry = (vi >> 1) & 1, rx = vi & 1;
    partial[(size_t)chunk * (B * 2 * HW) + (size_t)(b * 2 + co) * HW +
            (2 * y2 + ry) * W + (2 * x2b + rx)] = s;
  }
}

__global__ void k_fin_upfeat(const float* __restrict__ partial,
                             const float* __restrict__ bup,
                             float* __restrict__ feat,
                             unsigned short* __restrict__ featb) {
  int t = blockIdx.x * 256 + threadIdx.x;
  if (t >= B * 2 * HW) return;
  float s = 0.f;
#pragma unroll
  for (int c = 0; c < 7; ++c) s += partial[(size_t)c * (B * 2 * HW) + t];
  int rem = t % HW;
  int co = (t / HW) & 1;
  int b = t / (2 * HW);
  s += bup[co];
  feat[((size_t)b * FC + OFF_UPFEAT + co) * HW + rem] = s;
  featb[((size_t)(b * H) * W + rem) * FCP + OFF_UPFEAT + co] = f2b(s);
}

// ------------------------------- backwarp ----------------------------------
// Writes warped feat_2 as fp16 chunk-major: [3][B*HW][16ch].
__global__ __launch_bounds__(256) void k_backwarp(const float* __restrict__ feat2,
                                                  const float* __restrict__ feat,
                                                  unsigned short* __restrict__ warpedh) {
  int t = blockIdx.x * 256 + threadIdx.x;
  if (t >= B * HW) return;
  int x = t % W, y = (t / W) % H, b = t / HW;
  const float SX = 1.25f * (float)W / (float)(W - 1);
  const float SY = 1.25f * (float)H / (float)(H - 1);
  float fx = feat[(b * FC + OFF_UF + 0) * HW + y * W + x];
  float fy = feat[(b * FC + OFF_UF + 1) * HW + y * W + x];
  float px = (float)x + fx * SX;
  float py = (float)y + fy * SY;
  float x0f = floorf(px), y0f = floorf(py);
  int ix0 = (int)x0f, iy0 = (int)y0f;
  float wx1 = px - x0f, wx0 = 1.f - wx1;
  float wy1 = py - y0f, wy0 = 1.f - wy1;
  bool vx0 = (ix0 >= 0) & (ix0 < W), vx1 = (ix0 + 1 >= 0) & (ix0 + 1 < W);
  bool vy0 = (iy0 >= 0) & (iy0 < H), vy1 = (iy0 + 1 >= 0) & (iy0 + 1 < H);
  float w00 = (vx0 && vy0) ? wx0 * wy0 : 0.f;
  float w01 = (vx1 && vy0) ? wx1 * wy0 : 0.f;
  float w10 = (vx0 && vy1) ? wx0 * wy1 : 0.f;
  float w11 = (vx1 && vy1) ? wx1 * wy1 : 0.f;
  float wsum = w00 + w01 + w10 + w11;
  float m = wsum > 0.999f ? 1.f : 0.f;
  w00 *= m; w01 *= m; w10 *= m; w11 *= m;
  int cx0 = min(max(ix0, 0), W - 1), cx1 = min(max(ix0 + 1, 0), W - 1);
  int cy0 = min(max(iy0, 0), H - 1), cy1 = min(max(iy0 + 1, 0), H - 1);
  const float* s = feat2 + b * CF * HW;
  int o00 = cy0 * W + cx0, o01 = cy0 * W + cx1, o10 = cy1 * W + cx0, o11 = cy1 * W + cx1;
#pragma unroll 1
  for (int chunk = 0; chunk < 3; ++chunk) {
    h16x8 out0, out1;
#pragma unroll
    for (int k = 0; k < 16; ++k) {
      const float* sc = s + (chunk * 16 + k) * HW;
      float v = w00 * sc[o00] + w01 * sc[o01] + w10 * sc[o10] + w11 * sc[o11];
      if (k < 8) out0[k & 7] = (_Float16)v;
      else       out1[k & 7] = (_Float16)v;
    }
    h16x8* dst = (h16x8*)(warpedh + ((size_t)chunk * B * HW + t) * 16);
    dst[0] = out0;
    dst[1] = out1;
  }
}

// --------------------------- correlation + leaky ---------------------------
// grid = B*(H/2); 256 thr = 128 px x 2 rows. 3 chunks of 16 ch.
// LDS: [10 rows][136 px][16ch fp16 = 32B] with 16B-half swizzle h^=(p>>2)&1.
__global__ __launch_bounds__(256) void k_corr(const float* __restrict__ f1,
                                              const unsigned short* __restrict__ warpedh,
                                              float* __restrict__ feat,
                                              unsigned short* __restrict__ featb) {
  __shared__ __align__(16) unsigned short lds[10 * 136 * 16];
  const int tid = threadIdx.x;
  const int x = tid & 127, ys = tid >> 7;
  const int y0 = (blockIdx.x & 31) * 2, b = blockIdx.x >> 5;
  const int y = y0 + ys;
  const int pix = (b * H + y) * W + x;
  const int pixF = pix * FCP;
  float acc[81];
#pragma unroll
  for (int d = 0; d < 81; ++d) acc[d] = 0.f;
  uint4* lp = (uint4*)lds;
  const h16x8* hp = (const h16x8*)lds;
#pragma unroll 1
  for (int chunk = 0; chunk < 3; ++chunk) {
    __syncthreads();
    for (int i = tid; i < 1360; i += 256) {
      int r = i / 136, p = i - r * 136;
      int yy = y0 + r - 4, xx = p - 4;
      uint4 lo = {0, 0, 0, 0}, hi = {0, 0, 0, 0};
      if (yy >= 0 && yy < H && xx >= 0 && xx < W) {
        const uint4* g = (const uint4*)(warpedh +
            (((size_t)chunk * B * H + b * H + yy) * W + xx) * 16);
        lo = g[0];
        hi = g[1];
      }
      int sw = (p >> 2) & 1;
      int idx = (r * 136 + p) * 2;
      lp[idx + sw] = lo;
      lp[idx + (sw ^ 1)] = hi;
    }
    // f1 for this chunk: convert + free copies into feat/featb
    h16x2 fh[8];
#pragma unroll
    for (int k2 = 0; k2 < 8; ++k2) {
      int c0 = chunk * 16 + 2 * k2;
      float a0 = f1[((size_t)b * CF + c0) * HW + y * W + x];
      float a1 = f1[((size_t)b * CF + c0 + 1) * HW + y * W + x];
      feat[((size_t)b * FC + OFF_F1 + c0) * HW + y * W + x] = a0;
      feat[((size_t)b * FC + OFF_F1 + c0 + 1) * HW + y * W + x] = a1;
      featb[pixF + OFF_F1 + c0] = f2b(a0);
      featb[pixF + OFF_F1 + c0 + 1] = f2b(a1);
      fh[k2][0] = (_Float16)a0;
      fh[k2][1] = (_Float16)a1;
    }
    __syncthreads();
#pragma unroll
    for (int dy = 0; dy < 9; ++dy) {
#pragma unroll
      for (int dx = 0; dx < 9; ++dx) {
        int p = x + dx;
        int sw = (p >> 2) & 1;
        int base = ((ys + dy) * 136 + p) * 2;
        h16x8 lo = hp[base + sw];
        h16x8 hi = hp[base + (sw ^ 1)];
        float a = acc[dy * 9 + dx];
        a = __builtin_amdgcn_fdot2((h16x2){lo[0], lo[1]}, fh[0], a, false);
        a = __builtin_amdgcn_fdot2((h16x2){lo[2], lo[3]}, fh[1], a, false);
        a = __builtin_amdgcn_fdot2((h16x2){lo[4], lo[5]}, fh[2], a, false);
        a = __builtin_amdgcn_fdot2((h16x2){lo[6], lo[7]}, fh[3], a, false);
        a = __builtin_amdgcn_fdot2((h16x2){hi[0], hi[1]}, fh[4], a, false);
        a = __builtin_amdgcn_fdot2((h16x2){hi[2], hi[3]}, fh[5], a, false);
        a = __builtin_amdgcn_fdot2((h16x2){hi[4], hi[5]}, fh[6], a, false);
        a = __builtin_amdgcn_fdot2((h16x2){hi[6], hi[7]}, fh[7], a, false);
        acc[dy * 9 + dx] = a;
      }
    }
  }
  const float inv = 1.f / 48.f;
#pragma unroll
  for (int d = 0; d < 81; ++d) {
    float v = leaky(acc[d] * inv);
    acc[d] = v;
    feat[((size_t)b * FC + OFF_CORR + d) * HW + y * W + x] = v;
  }
  unsigned short* fb = featb + pixF + OFF_CORR;  // 16B-aligned (pix*544+272)
  uint4* fb4 = (uint4*)fb;
#pragma unroll
  for (int g = 0; g < 10; ++g) {
    uint4 q;
    q.x = (unsigned)f2b(acc[8 * g + 0]) | ((unsigned)f2b(acc[8 * g + 1]) << 16);
    q.y = (unsigned)f2b(acc[8 * g + 2]) | ((unsigned)f2b(acc[8 * g + 3]) << 16);
    q.z = (unsigned)f2b(acc[8 * g + 4]) | ((unsigned)f2b(acc[8 * g + 5]) << 16);
    q.w = (unsigned)f2b(acc[8 * g + 6]) | ((unsigned)f2b(acc[8 * g + 7]) << 16);
    fb4[g] = q;
  }
  fb[80] = f2b(acc[80]);
}

// ----------------- weight repack: f32 [co][ci][3][3] -> bf16 ---------------
template <int CIN, int NCHUNK, int COUT, int COUTP>
__global__ void k_repack(const float* __restrict__ w, unsigned short* __restrict__ wb) {
  int e = blockIdx.x * 256 + threadIdx.x;
  constexpr int TOT = NCHUNK * 9 * COUTP * 32;
  if (e >= TOT) return;
  int j = e & 7, qpos = (e >> 3) & 3;
  int row = e >> 5;
  int co = row % COUTP;
  int tapch = row / COUTP;
  int tap = tapch % 9, ch = tapch / 9;
  int ci = ch * 32 + ((qpos ^ ((co >> 1) & 3)) << 3) + j;
  float v = 0.f;
  if (co < COUT && ci < CIN) v = w[(co * CIN + ci) * 9 + tap];
  wb[e] = f2b(v);
}

// --------------------- conv3x3 + bias + leaky via MFMA ---------------------
template <int CIN, int NCHUNK, int COUT, int COUTP, int IN_OFF, int OUT_OFF, bool TO_FLOW>
__global__ __launch_bounds__(256) void k_conv_mfma(
    const unsigned short* __restrict__ featb, const unsigned short* __restrict__ wb,
    const float* __restrict__ bias, const unsigned short* __restrict__ zeros,
    float* __restrict__ fout, unsigned short* __restrict__ bout) {
  constexpr int NF = COUTP / 16;
  constexpr int ROWPX = 144;
  constexpr int IN_ELE = 3 * ROWPX * 32;
  constexpr int W_SLAB = 9 * COUTP * 32;
  constexpr int NIN = 27;
  constexpr int NWI = (W_SLAB * 2) / 1024;
  constexpr int NINST = NIN + NWI;
  constexpr int MYI = (NINST + 3) / 4;
  constexpr int CLIM = 264 - IN_OFF;

  __shared__ unsigned short lds[IN_ELE + W_SLAB];

  const int y = blockIdx.x % H, b = blockIdx.x / H;
  const int lane = threadIdx.x & 63, wv = threadIdx.x >> 6;
  const int arow = lane & 15, aslc = lane >> 4;

  const unsigned short* gp[MYI];
  int c8a[MYI];
  int lofs[MYI];
  bool iw[MYI];
#pragma unroll
  for (int t = 0; t < MYI; ++t) {
    int i = wv + t * 4;
    gp[t] = zeros; c8a[t] = 1 << 20; lofs[t] = 0; iw[t] = false;
    if (i < NIN) {
      int r = i / 9, seg = i - r * 9;
      int slot = seg * 16 + (lane >> 2);
      int sub8 = ((lane & 3) ^ ((slot >> 1) & 3)) << 3;
      int yy = y + r - 1, xx = slot - 1;
      lofs[t] = (r * ROWPX + seg * 16) * 64;
      if (yy >= 0 && yy < H && xx >= 0 && xx < W) {
        gp[t] = featb + ((b * H + yy) * W + xx) * FCP + IN_OFF + sub8;
        c8a[t] = sub8;
      }
    } else if (i < NINST) {
      int wi = i - NIN;
      iw[t] = true;
      gp[t] = wb + wi * 512 + lane * 8;
      lofs[t] = IN_ELE * 2 + wi * 1024;
    }
  }

  int a_off[2][3];
#pragma unroll
  for (int mi = 0; mi < 2; ++mi)
#pragma unroll
    for (int kx = 0; kx < 3; ++kx) {
      int slot = (wv * 2 + mi) * 16 + arow + kx;
      a_off[mi][kx] = slot * 32 + ((aslc ^ ((slot >> 1) & 3)) << 3);
    }
  int b_off[NF];
#pragma unroll
  for (int nf = 0; nf < NF; ++nf) {
    int co = nf * 16 + arow;
    b_off[nf] = IN_ELE + co * 32 + ((aslc ^ ((co >> 1) & 3)) << 3);
  }

  f32x4 acc[2][NF];
#pragma unroll
  for (int mi = 0; mi < 2; ++mi)
#pragma unroll
    for (int nf = 0; nf < NF; ++nf) acc[mi][nf] = (f32x4){0.f, 0.f, 0.f, 0.f};

  char* ldsc = (char*)lds;

  for (int ch = 0; ch < NCHUNK; ++ch) {
    const int ci0 = ch * 32;
    __syncthreads();
#pragma unroll
    for (int t = 0; t < MYI; ++t) {
      int i = wv + t * 4;
      if (i < NINST) {
        const unsigned short* g;
        if (iw[t]) g = gp[t] + (size_t)ch * W_SLAB;
        else       g = (c8a[t] + ci0 <= CLIM) ? gp[t] + ci0 : zeros;
        gload16(g, ldsc + lofs[t]);
      }
    }
    asm volatile("s_waitcnt vmcnt(0)" ::: "memory");
    __syncthreads();
#pragma unroll
    for (int ky = 0; ky < 3; ++ky) {
#pragma unroll
      for (int kx = 0; kx < 3; ++kx) {
        bf16x8 afr[2];
#pragma unroll
        for (int mi = 0; mi < 2; ++mi)
          afr[mi] = *(const bf16x8*)(lds + a_off[mi][kx] + ky * (ROWPX * 32));
#pragma unroll
        for (int nf = 0; nf < NF; ++nf) {
          bf16x8 bfr = *(const bf16x8*)(lds + b_off[nf] + (ky * 3 + kx) * (COUTP * 32));
#pragma unroll
          for (int mi = 0; mi < 2; ++mi)
            acc[mi][nf] = __builtin_amdgcn_mfma_f32_16x16x32_bf16(
                afr[mi], bfr, acc[mi][nf], 0, 0, 0);
        }
      }
    }
  }

  const int dcol = lane & 15;
#pragma unroll
  for (int nf = 0; nf < NF; ++nf) {
    int co = nf * 16 + dcol;
    if (co < COUT) {
      float bv = bias[co];
#pragma unroll
      for (int mi = 0; mi < 2; ++mi) {
#pragma unroll
        for (int r = 0; r < 4; ++r) {
          int pixel = (wv * 2 + mi) * 16 + (lane >> 4) * 4 + r;
          float v = leaky(acc[mi][nf][r] + bv);
          if constexpr (TO_FLOW) {
            fout[(b * 2 + co) * HW + y * W + pixel] = v;
          } else {
            fout[(b * FC + OUT_OFF + co) * HW + y * W + pixel] = v;
            bout[((b * H + y) * W + pixel) * FCP + OUT_OFF + co] = f2b(v);
          }
        }
      }
    }
  }
}

// ---------------------------------------------------------------------------
extern "C" void kernel_launch(void* const* d_in, const int* in_sizes, int n_in,
                              void* d_out, int out_size, void* d_ws, size_t ws_size,
                              hipStream_t stream) {
  (void)in_sizes; (void)n_in; (void)out_size; (void)ws_size;
  const float* feat_1 = (const float*)d_in[0];
  const float* feat_2 = (const float*)d_in[1];
  const float* prev_flow = (const float*)d_in[2];
  const float* prev_feat = (const float*)d_in[3];
  const float* w1 = (const float*)d_in[4];
  const float* b1 = (const float*)d_in[5];
  const float* w2 = (const float*)d_in[6];
  const float* b2 = (const float*)d_in[7];
  const float* w3 = (const float*)d_in[8];
  const float* b3 = (const float*)d_in[9];
  const float* w4 = (const float*)d_in[10];
  const float* b4 = (const float*)d_in[11];
  const float* w5 = (const float*)d_in[12];
  const float* b5 = (const float*)d_in[13];
  const float* w_upflow = (const float*)d_in[14];
  const float* b_upflow = (const float*)d_in[15];
  const float* w_upfeat = (const float*)d_in[16];
  const float* b_upfeat = (const float*)d_in[17];

  float* out = (float*)d_out;
  float* feat = out + FLOW_ELEMS;

  char* ws = (char*)d_ws;
  unsigned short* zeros = (unsigned short*)(ws + WS_ZEROS);
  unsigned short* featb = (unsigned short*)(ws + WS_FEATB);
  unsigned short* warpedh = (unsigned short*)(ws + WS_WARPEDH);
  float* partial = (float*)(ws + WS_PART);
  unsigned short* wb1 = (unsigned short*)(ws + WS_WB);
  unsigned short* wb2 = wb1 + 5 * 9 * 48 * 32;
  unsigned short* wb3 = wb2 + 6 * 9 * 48 * 32;
  unsigned short* wb4 = wb3 + 8 * 9 * 32 * 32;
  unsigned short* wb5 = wb4 + 8 * 9 * 16 * 32;

  hipMemsetAsync(zeros, 0, 64, stream);

  k_repack<133, 5, 48, 48><<<270, 256, 0, stream>>>(w1, wb1);
  k_repack<181, 6, 48, 48><<<324, 256, 0, stream>>>(w2, wb2);
  k_repack<229, 8, 24, 32><<<288, 256, 0, stream>>>(w3, wb3);
  k_repack<253, 8, 16, 16><<<144, 256, 0, stream>>>(w4, wb4);
  k_repack<269, 9, 2, 16><<<162, 256, 0, stream>>>(w5, wb5);

  k_deconv_flow<<<(B * 2 * HW) / 256, 256, 0, stream>>>(prev_flow, w_upflow, b_upflow, feat, featb);
  k_dcf_part<<<B * H2 * 7, 256, 0, stream>>>(prev_feat, w_upfeat, partial);
  k_fin_upfeat<<<(B * 2 * HW) / 256, 256, 0, stream>>>(partial, b_upfeat, feat, featb);
  k_backwarp<<<(B * HW) / 256, 256, 0, stream>>>(feat_2, feat, warpedh);
  k_corr<<<B * (H / 2), 256, 0, stream>>>(feat_1, warpedh, feat, featb);

  k_conv_mfma<133, 5, 48, 48, 136, 88, false><<<B * H, 256, 0, stream>>>(featb, wb1, b1, zeros, feat, featb);
  k_conv_mfma<181, 6, 48, 48, 88, 40, false><<<B * H, 256, 0, stream>>>(featb, wb2, b2, zeros, feat, featb);
  k_conv_mfma<229, 8, 24, 32, 40, 16, false><<<B * H, 256, 0, stream>>>(featb, wb3, b3, zeros, feat, featb);
  k_conv_mfma<253, 8, 16, 16, 16, 0, false><<<B * H, 256, 0, stream>>>(featb, wb4, b4, zeros, feat, featb);
  k_conv_mfma<269, 9, 2, 16, 0, 0, true><<<B * H, 256, 0, stream>>>(featb, wb5, b5, zeros, out, nullptr);
}

// Round 4
// 296.077 us; speedup vs baseline: 9.0096x; 1.6110x over previous
//
#include <hip/hip_runtime.h>

// ---------------------------------------------------------------------------
// PWC-Net decoder level (B=16, C=48, H=64, W=128) — MFMA implicit-GEMM convs.
// d_out = [flow 16*2*64*128][feat_out 16*269*64*128] (f32)
// Reference out-channel order: [c4 0..15][c3 16..39][c2 40..87][c1 88..135]
//                    [corr 136..216][feat1 217..264][upflow 265..266][upfeat 267..268]
// featb (bf16 [B][H][W][272]) uses a PERMUTED channel order for aligned writes:
//   [c4 0..15][c3 16..39][c2 40..87][c1 88..135][f1 136..183][corr 184..264]
//   [upflow 265..266][upfeat 267..268][pad 269..271]
// The permutation is baked into the conv weight repack (featb2ref).
// ---------------------------------------------------------------------------

#define DEVFN __device__ __forceinline__

constexpr int B = 16, H = 64, W = 128, HW = H * W;
constexpr int CF = 48;
constexpr int PFC = 217;
constexpr int H2 = 32, W2 = 64, HW2 = H2 * W2;
constexpr int FC = 269;
constexpr int FCP = 272;
constexpr int FLOW_ELEMS = B * 2 * HW;

// reference (output) channel offsets
constexpr int OFF_CORR = 136, OFF_F1 = 217, OFF_UF = 265, OFF_UPFEAT = 267;
// featb channel offsets
constexpr int FB_F1 = 136, FB_CORR = 184;

// ws layout (bytes)
constexpr size_t WS_ZEROS = 0;
constexpr size_t WS_FEATB = 256;
constexpr size_t FEATB_BYTES = (size_t)B * HW * FCP * 2;      // 71,303,168
constexpr size_t WS_WARPEDH = WS_FEATB + FEATB_BYTES;
constexpr size_t WARPEDH_BYTES = (size_t)3 * B * HW * 16 * 2; // 12,582,912
constexpr size_t WS_PART = WS_WARPEDH + WARPEDH_BYTES;
constexpr size_t PART_BYTES = (size_t)7 * B * 2 * HW * 4;     // 7,340,032
constexpr size_t WS_WB = WS_PART + PART_BYTES;

typedef short bf16x8 __attribute__((ext_vector_type(8)));
typedef float f32x4 __attribute__((ext_vector_type(4)));
typedef _Float16 h16x2 __attribute__((ext_vector_type(2)));
typedef _Float16 h16x8 __attribute__((ext_vector_type(8)));

DEVFN float leaky(float x) { return x >= 0.f ? x : 0.1f * x; }

DEVFN unsigned short f2b(float f) {  // RNE f32 -> bf16
  unsigned int u = __float_as_uint(f);
  u += 0x7FFFu + ((u >> 16) & 1u);
  return (unsigned short)(u >> 16);
}

DEVFN void gload16(const void* g, void* l) {
  __builtin_amdgcn_global_load_lds(
      (const __attribute__((address_space(1))) void*)g,
      (__attribute__((address_space(3))) void*)l, 16, 0, 0);
}

// featb position -> reference conv-input global channel
DEVFN int featb2ref(int p) {
  if (p >= FB_F1 && p < FB_CORR) return OFF_F1 + (p - FB_F1);     // f1
  if (p >= FB_CORR && p < 265) return OFF_CORR + (p - FB_CORR);   // corr
  return p;
}

// ------------------------- deconv4x4 s2 on prev_flow -----------------------
__global__ void k_deconv_flow(const float* __restrict__ pflow,
                              const float* __restrict__ wuf,
                              const float* __restrict__ buf_,
                              float* __restrict__ feat,
                              unsigned short* __restrict__ featb) {
  int t = blockIdx.x * blockDim.x + threadIdx.x;
  if (t >= B * 2 * HW) return;
  int x = t % W, y = (t / W) % H, co = (t / HW) % 2, b = t / (2 * HW);
  float acc = buf_[co];
  int ky0 = ((y & 1) == 0) ? 1 : 0;
  int kx0 = ((x & 1) == 0) ? 1 : 0;
#pragma unroll
  for (int kyi = 0; kyi < 2; ++kyi) {
    int ky = ky0 + 2 * kyi;
    int iy = (y + 1 - ky) >> 1;
    if (iy < 0 || iy >= H2) continue;
#pragma unroll
    for (int kxi = 0; kxi < 2; ++kxi) {
      int kx = kx0 + 2 * kxi;
      int ix = (x + 1 - kx) >> 1;
      if (ix < 0 || ix >= W2) continue;
#pragma unroll
      for (int ci = 0; ci < 2; ++ci)
        acc += pflow[(b * 2 + ci) * HW2 + iy * W2 + ix] *
               wuf[((ci * 2 + co) * 4 + ky) * 4 + kx];
    }
  }
  int pix = (b * H + y) * W + x;
  feat[(b * FC + OFF_UF + co) * HW + y * W + x] = acc;
  featb[pix * FCP + OFF_UF + co] = f2b(acc);
  if (co == 0) {
    featb[pix * FCP + 269] = 0;
    featb[pix * FCP + 270] = 0;
    featb[pix * FCP + 271] = 0;
  }
}

// ----------------- deconv4x4 s2 on prev_feat: partial pass -----------------
__global__ __launch_bounds__(256) void k_dcf_part(
    const float* __restrict__ pfeat, const float* __restrict__ wup,
    float* __restrict__ partial) {
  __shared__ float wl[1024];
  __shared__ float red[2048];
  int blk = blockIdx.x;
  int chunk = blk % 7, t2 = blk / 7;
  int y2 = t2 % H2, b = t2 / H2;
  int tid = threadIdx.x;
  int ch0 = chunk * 32;
  for (int i = tid; i < 1024; i += 256) {
    int ci = ch0 + (i >> 5);
    wl[i] = (ci < PFC) ? wup[ci * 32 + (i & 31)] : 0.f;
  }
  __syncthreads();
  int x2 = tid & 63, cg = tid >> 6;
  float acc[8];
#pragma unroll
  for (int v = 0; v < 8; ++v) acc[v] = 0.f;
#pragma unroll 1
  for (int k = 0; k < 8; ++k) {
    int cil = cg * 8 + k;
    int ci = ch0 + cil;
    bool cv = ci < PFC;
    const float* src = pfeat + ((size_t)b * PFC + ci) * HW2;
    float iv[3][3];
#pragma unroll
    for (int dy = -1; dy <= 1; ++dy)
#pragma unroll
      for (int dx = -1; dx <= 1; ++dx) {
        int iy = y2 + dy, ix = x2 + dx;
        float v = 0.f;
        if (cv && iy >= 0 && iy < H2 && ix >= 0 && ix < W2) v = src[iy * W2 + ix];
        iv[dy + 1][dx + 1] = v;
      }
    const float* wc = &wl[cil * 32];
#pragma unroll
    for (int co = 0; co < 2; ++co)
#pragma unroll
      for (int ry = 0; ry < 2; ++ry)
#pragma unroll
        for (int rx = 0; rx < 2; ++rx) {
          float s = acc[co * 4 + ry * 2 + rx];
#pragma unroll
          for (int dy = ry - 1; dy <= ry; ++dy) {
            int ky = 1 + ry - 2 * dy;
#pragma unroll
            for (int dx = rx - 1; dx <= rx; ++dx) {
              int kx = 1 + rx - 2 * dx;
              s += iv[dy + 1][dx + 1] * wc[co * 16 + ky * 4 + kx];
            }
          }
          acc[co * 4 + ry * 2 + rx] = s;
        }
  }
#pragma unroll
  for (int v = 0; v < 8; ++v) red[(cg * 64 + x2) * 8 + v] = acc[v];
  __syncthreads();
  for (int idx = tid; idx < 512; idx += 256) {
    int x2b = idx & 63, vi = idx >> 6;
    float s = red[(0 + x2b) * 8 + vi] + red[(64 + x2b) * 8 + vi] +
              red[(128 + x2b) * 8 + vi] + red[(192 + x2b) * 8 + vi];
    int co = vi >> 2, ry = (vi >> 1) & 1, rx = vi & 1;
    partial[(size_t)chunk * (B * 2 * HW) + (size_t)(b * 2 + co) * HW +
            (2 * y2 + ry) * W + (2 * x2b + rx)] = s;
  }
}

__global__ void k_fin_upfeat(const float* __restrict__ partial,
                             const float* __restrict__ bup,
                             float* __restrict__ feat,
                             unsigned short* __restrict__ featb) {
  int t = blockIdx.x * 256 + threadIdx.x;
  if (t >= B * 2 * HW) return;
  float s = 0.f;
#pragma unroll
  for (int c = 0; c < 7; ++c) s += partial[(size_t)c * (B * 2 * HW) + t];
  int rem = t % HW;
  int co = (t / HW) & 1;
  int b = t / (2 * HW);
  s += bup[co];
  feat[((size_t)b * FC + OFF_UPFEAT + co) * HW + rem] = s;
  featb[((size_t)(b * H) * W + rem) * FCP + OFF_UPFEAT + co] = f2b(s);
}

// ------------------------------- backwarp ----------------------------------
__global__ __launch_bounds__(256) void k_backwarp(const float* __restrict__ feat2,
                                                  const float* __restrict__ feat,
                                                  unsigned short* __restrict__ warpedh) {
  int t = blockIdx.x * 256 + threadIdx.x;
  if (t >= B * HW) return;
  int x = t % W, y = (t / W) % H, b = t / HW;
  const float SX = 1.25f * (float)W / (float)(W - 1);
  const float SY = 1.25f * (float)H / (float)(H - 1);
  float fx = feat[(b * FC + OFF_UF + 0) * HW + y * W + x];
  float fy = feat[(b * FC + OFF_UF + 1) * HW + y * W + x];
  float px = (float)x + fx * SX;
  float py = (float)y + fy * SY;
  float x0f = floorf(px), y0f = floorf(py);
  int ix0 = (int)x0f, iy0 = (int)y0f;
  float wx1 = px - x0f, wx0 = 1.f - wx1;
  float wy1 = py - y0f, wy0 = 1.f - wy1;
  bool vx0 = (ix0 >= 0) & (ix0 < W), vx1 = (ix0 + 1 >= 0) & (ix0 + 1 < W);
  bool vy0 = (iy0 >= 0) & (iy0 < H), vy1 = (iy0 + 1 >= 0) & (iy0 + 1 < H);
  float w00 = (vx0 && vy0) ? wx0 * wy0 : 0.f;
  float w01 = (vx1 && vy0) ? wx1 * wy0 : 0.f;
  float w10 = (vx0 && vy1) ? wx0 * wy1 : 0.f;
  float w11 = (vx1 && vy1) ? wx1 * wy1 : 0.f;
  float wsum = w00 + w01 + w10 + w11;
  float m = wsum > 0.999f ? 1.f : 0.f;
  w00 *= m; w01 *= m; w10 *= m; w11 *= m;
  int cx0 = min(max(ix0, 0), W - 1), cx1 = min(max(ix0 + 1, 0), W - 1);
  int cy0 = min(max(iy0, 0), H - 1), cy1 = min(max(iy0 + 1, 0), H - 1);
  const float* s = feat2 + b * CF * HW;
  int o00 = cy0 * W + cx0, o01 = cy0 * W + cx1, o10 = cy1 * W + cx0, o11 = cy1 * W + cx1;
#pragma unroll 1
  for (int chunk = 0; chunk < 3; ++chunk) {
    h16x8 out0, out1;
#pragma unroll
    for (int k = 0; k < 16; ++k) {
      const float* sc = s + (chunk * 16 + k) * HW;
      float v = w00 * sc[o00] + w01 * sc[o01] + w10 * sc[o10] + w11 * sc[o11];
      if (k < 8) out0[k & 7] = (_Float16)v;
      else       out1[k & 7] = (_Float16)v;
    }
    h16x8* dst = (h16x8*)(warpedh + ((size_t)chunk * B * HW + t) * 16);
    dst[0] = out0;
    dst[1] = out1;
  }
}

// --------------------------- correlation + leaky ---------------------------
// grid = B*H (XCD-swizzled), 256 thr: px = tid>>1 (128 px), h = tid&1
// (channel half). Two passes: dy 0..4 (45 disp) and dy 5..8 (36 disp).
// Per pass: 3 chunks of 16 ch staged [R][136][16] fp16 via global_load_lds
// with lo/hi swizzle encoded in per-lane global source. Pair-reduce via
// shfl_xor(1); even lane writes f32 corr (ref order), odd lane writes featb.
__global__ __launch_bounds__(256) void k_corr(const float* __restrict__ f1,
                                              const unsigned short* __restrict__ warpedh,
                                              const unsigned short* __restrict__ zeros,
                                              float* __restrict__ feat,
                                              unsigned short* __restrict__ featb) {
  __shared__ __align__(16) unsigned short lds[5 * 136 * 16];  // 21760 B
  const int swz = ((blockIdx.x & 7) << 7) | (blockIdx.x >> 3);
  const int y = swz & 63, b = swz >> 6;
  const int tid = threadIdx.x;
  const int px = tid >> 1, h = tid & 1;
  const int lane = tid & 63, wv = tid >> 6;
  const int pix = (b * H + y) * W + px;
  const h16x8* hp = (const h16x8*)lds;
  char* ldsc = (char*)lds;
  const float inv = 1.f / 48.f;

#pragma unroll 1
  for (int half = 0; half < 2; ++half) {
    const int R = half ? 4 : 5;
    const int dybase = half ? 5 : 0;
    const int ND = R * 9;
    float acc[45];
#pragma unroll
    for (int d = 0; d < 45; ++d) acc[d] = 0.f;
#pragma unroll 1
    for (int chunk = 0; chunk < 3; ++chunk) {
      __syncthreads();
      const int NQ = R * 136 * 2;  // 16B granules to stage
      for (int q0 = 0; q0 < NQ; q0 += 256) {
        int q = q0 + tid;
        if (q < NQ) {
          int pr = q >> 1, u = q & 1;
          int r = pr / 136, p = pr - r * 136;
          int sw = (p >> 2) & 1;
          int yy = y + dybase + r - 4, xx = p - 4;
          const unsigned short* src = zeros;
          if (yy >= 0 && yy < H && xx >= 0 && xx < W)
            src = warpedh + (((size_t)chunk * B * H + b * H + yy) * W + xx) * 16 +
                  (u ^ sw) * 8;
          gload16(src, ldsc + (size_t)q0 * 16 + wv * 1024 + lane * 16);
        }
      }
      // f1 fragment for this (chunk, h)
      float av[8];
      const int c0 = chunk * 16 + h * 8;
#pragma unroll
      for (int j = 0; j < 8; ++j)
        av[j] = f1[((size_t)b * CF + c0 + j) * HW + y * W + px];
      h16x2 fh[4];
#pragma unroll
      for (int j = 0; j < 4; ++j) {
        fh[j][0] = (_Float16)av[2 * j];
        fh[j][1] = (_Float16)av[2 * j + 1];
      }
      asm volatile("s_waitcnt vmcnt(0)" ::: "memory");
      __syncthreads();
      if (half == 0) {  // f1 copies (once)
#pragma unroll
        for (int j = 0; j < 8; ++j)
          feat[((size_t)b * FC + OFF_F1 + c0 + j) * HW + y * W + px] = av[j];
        uint4 qv;
        qv.x = (unsigned)f2b(av[0]) | ((unsigned)f2b(av[1]) << 16);
        qv.y = (unsigned)f2b(av[2]) | ((unsigned)f2b(av[3]) << 16);
        qv.z = (unsigned)f2b(av[4]) | ((unsigned)f2b(av[5]) << 16);
        qv.w = (unsigned)f2b(av[6]) | ((unsigned)f2b(av[7]) << 16);
        *(uint4*)(featb + (size_t)pix * FCP + FB_F1 + c0) = qv;
      }
#pragma unroll
      for (int dy = 0; dy < 5; ++dy) {
        if (dy < R) {
#pragma unroll
          for (int dx = 0; dx < 9; ++dx) {
            int p = px + dx;
            int sw = (p >> 2) & 1;
            h16x8 v = hp[((dy * 136 + p) << 1) | (h ^ sw)];
            float a = acc[dy * 9 + dx];
            a = __builtin_amdgcn_fdot2((h16x2){v[0], v[1]}, fh[0], a, false);
            a = __builtin_amdgcn_fdot2((h16x2){v[2], v[3]}, fh[1], a, false);
            a = __builtin_amdgcn_fdot2((h16x2){v[4], v[5]}, fh[2], a, false);
            a = __builtin_amdgcn_fdot2((h16x2){v[6], v[7]}, fh[3], a, false);
            acc[dy * 9 + dx] = a;
          }
        }
      }
    }
    // pair-reduce + activation
#pragma unroll
    for (int d = 0; d < 45; ++d) {
      if (d < ND) {
        float s = acc[d] + __shfl_xor(acc[d], 1);
        acc[d] = leaky(s * inv);
      }
    }
    if (h == 0) {  // f32 corr in reference order
#pragma unroll
      for (int d = 0; d < 45; ++d)
        if (d < ND)
          feat[((size_t)b * FC + OFF_CORR + dybase * 9 + d) * HW + y * W + px] = acc[d];
    } else {  // featb corr (bf16) at FB_CORR
      unsigned short* fb = featb + (size_t)pix * FCP + FB_CORR + dybase * 9;
      if (half == 0) {  // pos 184..228: 5 x uint4 + 5 scalars
#pragma unroll
        for (int g = 0; g < 5; ++g) {
          uint4 qv;
          qv.x = (unsigned)f2b(acc[8 * g + 0]) | ((unsigned)f2b(acc[8 * g + 1]) << 16);
          qv.y = (unsigned)f2b(acc[8 * g + 2]) | ((unsigned)f2b(acc[8 * g + 3]) << 16);
          qv.z = (unsigned)f2b(acc[8 * g + 4]) | ((unsigned)f2b(acc[8 * g + 5]) << 16);
          qv.w = (unsigned)f2b(acc[8 * g + 6]) | ((unsigned)f2b(acc[8 * g + 7]) << 16);
          *(uint4*)(fb + 8 * g) = qv;
        }
#pragma unroll
        for (int d = 40; d < 45; ++d) fb[d] = f2b(acc[d]);
      } else {  // pos 229..264: 3 scalars + 4 x uint4 + 1 scalar
        fb[0] = f2b(acc[0]);
        fb[1] = f2b(acc[1]);
        fb[2] = f2b(acc[2]);
#pragma unroll
        for (int g = 0; g < 4; ++g) {
          uint4 qv;
          qv.x = (unsigned)f2b(acc[3 + 8 * g + 0]) | ((unsigned)f2b(acc[3 + 8 * g + 1]) << 16);
          qv.y = (unsigned)f2b(acc[3 + 8 * g + 2]) | ((unsigned)f2b(acc[3 + 8 * g + 3]) << 16);
          qv.z = (unsigned)f2b(acc[3 + 8 * g + 4]) | ((unsigned)f2b(acc[3 + 8 * g + 5]) << 16);
          qv.w = (unsigned)f2b(acc[3 + 8 * g + 6]) | ((unsigned)f2b(acc[3 + 8 * g + 7]) << 16);
          *(uint4*)(fb + 3 + 8 * g) = qv;
        }
        fb[35] = f2b(acc[35]);
      }
    }
  }
}

// ----------------- weight repack: f32 [co][ci][3][3] -> bf16 ---------------
// wb layout: [chunk][tap][co][qpos][j] (32 featb-positions per chunk, swizzle
// baked). ci maps through featb2ref to handle the f1/corr permutation.
template <int CIN, int NCHUNK, int COUT, int COUTP, int IN_OFF>
__global__ void k_repack(const float* __restrict__ w, unsigned short* __restrict__ wb) {
  int e = blockIdx.x * 256 + threadIdx.x;
  constexpr int TOT = NCHUNK * 9 * COUTP * 32;
  if (e >= TOT) return;
  int j = e & 7, qpos = (e >> 3) & 3;
  int row = e >> 5;
  int co = row % COUTP;
  int tapch = row / COUTP;
  int tap = tapch % 9, ch = tapch / 9;
  int k = ch * 32 + ((qpos ^ ((co >> 1) & 3)) << 3) + j;  // featb-suffix index
  float v = 0.f;
  if (co < COUT && k < CIN) {
    int ci = featb2ref(IN_OFF + k) - IN_OFF;  // reference ci
    v = w[(co * CIN + ci) * 9 + tap];
  }
  wb[e] = f2b(v);
}

// --------------------- conv3x3 + bias + leaky via MFMA ---------------------
template <int CIN, int NCHUNK, int COUT, int COUTP, int IN_OFF, int OUT_OFF, bool TO_FLOW>
__global__ __launch_bounds__(256) void k_conv_mfma(
    const unsigned short* __restrict__ featb, const unsigned short* __restrict__ wb,
    const float* __restrict__ bias, const unsigned short* __restrict__ zeros,
    float* __restrict__ fout, unsigned short* __restrict__ bout) {
  constexpr int NF = COUTP / 16;
  constexpr int ROWPX = 144;
  constexpr int IN_ELE = 3 * ROWPX * 32;
  constexpr int W_SLAB = 9 * COUTP * 32;
  constexpr int NIN = 27;
  constexpr int NWI = (W_SLAB * 2) / 1024;
  constexpr int NINST = NIN + NWI;
  constexpr int MYI = (NINST + 3) / 4;
  constexpr int CLIM = 264 - IN_OFF;

  __shared__ unsigned short lds[IN_ELE + W_SLAB];

  const int swz = ((blockIdx.x & 7) << 7) | (blockIdx.x >> 3);
  const int y = swz % H, b = swz / H;
  const int lane = threadIdx.x & 63, wv = threadIdx.x >> 6;
  const int arow = lane & 15, aslc = lane >> 4;

  const unsigned short* gp[MYI];
  int c8a[MYI];
  int lofs[MYI];
  bool iw[MYI];
#pragma unroll
  for (int t = 0; t < MYI; ++t) {
    int i = wv + t * 4;
    gp[t] = zeros; c8a[t] = 1 << 20; lofs[t] = 0; iw[t] = false;
    if (i < NIN) {
      int r = i / 9, seg = i - r * 9;
      int slot = seg * 16 + (lane >> 2);
      int sub8 = ((lane & 3) ^ ((slot >> 1) & 3)) << 3;
      int yy = y + r - 1, xx = slot - 1;
      lofs[t] = (r * ROWPX + seg * 16) * 64;
      if (yy >= 0 && yy < H && xx >= 0 && xx < W) {
        gp[t] = featb + ((b * H + yy) * W + xx) * FCP + IN_OFF + sub8;
        c8a[t] = sub8;
      }
    } else if (i < NINST) {
      int wi = i - NIN;
      iw[t] = true;
      gp[t] = wb + wi * 512 + lane * 8;
      lofs[t] = IN_ELE * 2 + wi * 1024;
    }
  }

  int a_off[2][3];
#pragma unroll
  for (int mi = 0; mi < 2; ++mi)
#pragma unroll
    for (int kx = 0; kx < 3; ++kx) {
      int slot = (wv * 2 + mi) * 16 + arow + kx;
      a_off[mi][kx] = slot * 32 + ((aslc ^ ((slot >> 1) & 3)) << 3);
    }
  int b_off[NF];
#pragma unroll
  for (int nf = 0; nf < NF; ++nf) {
    int co = nf * 16 + arow;
    b_off[nf] = IN_ELE + co * 32 + ((aslc ^ ((co >> 1) & 3)) << 3);
  }

  f32x4 acc[2][NF];
#pragma unroll
  for (int mi = 0; mi < 2; ++mi)
#pragma unroll
    for (int nf = 0; nf < NF; ++nf) acc[mi][nf] = (f32x4){0.f, 0.f, 0.f, 0.f};

  char* ldsc = (char*)lds;

  for (int ch = 0; ch < NCHUNK; ++ch) {
    const int ci0 = ch * 32;
    __syncthreads();
#pragma unroll
    for (int t = 0; t < MYI; ++t) {
      int i = wv + t * 4;
      if (i < NINST) {
        const unsigned short* g;
        if (iw[t]) g = gp[t] + (size_t)ch * W_SLAB;
        else       g = (c8a[t] + ci0 <= CLIM) ? gp[t] + ci0 : zeros;
        gload16(g, ldsc + lofs[t]);
      }
    }
    asm volatile("s_waitcnt vmcnt(0)" ::: "memory");
    __syncthreads();
#pragma unroll
    for (int ky = 0; ky < 3; ++ky) {
#pragma unroll
      for (int kx = 0; kx < 3; ++kx) {
        bf16x8 afr[2];
#pragma unroll
        for (int mi = 0; mi < 2; ++mi)
          afr[mi] = *(const bf16x8*)(lds + a_off[mi][kx] + ky * (ROWPX * 32));
#pragma unroll
        for (int nf = 0; nf < NF; ++nf) {
          bf16x8 bfr = *(const bf16x8*)(lds + b_off[nf] + (ky * 3 + kx) * (COUTP * 32));
#pragma unroll
          for (int mi = 0; mi < 2; ++mi)
            acc[mi][nf] = __builtin_amdgcn_mfma_f32_16x16x32_bf16(
                afr[mi], bfr, acc[mi][nf], 0, 0, 0);
        }
      }
    }
  }

  const int dcol = lane & 15;
#pragma unroll
  for (int nf = 0; nf < NF; ++nf) {
    int co = nf * 16 + dcol;
    if (co < COUT) {
      float bv = bias[co];
#pragma unroll
      for (int mi = 0; mi < 2; ++mi) {
#pragma unroll
        for (int r = 0; r < 4; ++r) {
          int pixel = (wv * 2 + mi) * 16 + (lane >> 4) * 4 + r;
          float v = leaky(acc[mi][nf][r] + bv);
          if constexpr (TO_FLOW) {
            fout[(b * 2 + co) * HW + y * W + pixel] = v;
          } else {
            fout[(b * FC + OUT_OFF + co) * HW + y * W + pixel] = v;
            bout[((b * H + y) * W + pixel) * FCP + OUT_OFF + co] = f2b(v);
          }
        }
      }
    }
  }
}

// ---------------------------------------------------------------------------
extern "C" void kernel_launch(void* const* d_in, const int* in_sizes, int n_in,
                              void* d_out, int out_size, void* d_ws, size_t ws_size,
                              hipStream_t stream) {
  (void)in_sizes; (void)n_in; (void)out_size; (void)ws_size;
  const float* feat_1 = (const float*)d_in[0];
  const float* feat_2 = (const float*)d_in[1];
  const float* prev_flow = (const float*)d_in[2];
  const float* prev_feat = (const float*)d_in[3];
  const float* w1 = (const float*)d_in[4];
  const float* b1 = (const float*)d_in[5];
  const float* w2 = (const float*)d_in[6];
  const float* b2 = (const float*)d_in[7];
  const float* w3 = (const float*)d_in[8];
  const float* b3 = (const float*)d_in[9];
  const float* w4 = (const float*)d_in[10];
  const float* b4 = (const float*)d_in[11];
  const float* w5 = (const float*)d_in[12];
  const float* b5 = (const float*)d_in[13];
  const float* w_upflow = (const float*)d_in[14];
  const float* b_upflow = (const float*)d_in[15];
  const float* w_upfeat = (const float*)d_in[16];
  const float* b_upfeat = (const float*)d_in[17];

  float* out = (float*)d_out;
  float* feat = out + FLOW_ELEMS;

  char* ws = (char*)d_ws;
  unsigned short* zeros = (unsigned short*)(ws + WS_ZEROS);
  unsigned short* featb = (unsigned short*)(ws + WS_FEATB);
  unsigned short* warpedh = (unsigned short*)(ws + WS_WARPEDH);
  float* partial = (float*)(ws + WS_PART);
  unsigned short* wb1 = (unsigned short*)(ws + WS_WB);
  unsigned short* wb2 = wb1 + 5 * 9 * 48 * 32;
  unsigned short* wb3 = wb2 + 6 * 9 * 48 * 32;
  unsigned short* wb4 = wb3 + 8 * 9 * 32 * 32;
  unsigned short* wb5 = wb4 + 8 * 9 * 16 * 32;

  hipMemsetAsync(zeros, 0, 64, stream);

  k_repack<133, 5, 48, 48, 136><<<270, 256, 0, stream>>>(w1, wb1);
  k_repack<181, 6, 48, 48, 88><<<324, 256, 0, stream>>>(w2, wb2);
  k_repack<229, 8, 24, 32, 40><<<288, 256, 0, stream>>>(w3, wb3);
  k_repack<253, 8, 16, 16, 16><<<144, 256, 0, stream>>>(w4, wb4);
  k_repack<269, 9, 2, 16, 0><<<162, 256, 0, stream>>>(w5, wb5);

  k_deconv_flow<<<(B * 2 * HW) / 256, 256, 0, stream>>>(prev_flow, w_upflow, b_upflow, feat, featb);
  k_dcf_part<<<B * H2 * 7, 256, 0, stream>>>(prev_feat, w_upfeat, partial);
  k_fin_upfeat<<<(B * 2 * HW) / 256, 256, 0, stream>>>(partial, b_upfeat, feat, featb);
  k_backwarp<<<(B * HW) / 256, 256, 0, stream>>>(feat_2, feat, warpedh);
  k_corr<<<B * H, 256, 0, stream>>>(feat_1, warpedh, zeros, feat, featb);

  k_conv_mfma<133, 5, 48, 48, 136, 88, false><<<B * H, 256, 0, stream>>>(featb, wb1, b1, zeros, feat, featb);
  k_conv_mfma<181, 6, 48, 48, 88, 40, false><<<B * H, 256, 0, stream>>>(featb, wb2, b2, zeros, feat, featb);
  k_conv_mfma<229, 8, 24, 32, 40, 16, false><<<B * H, 256, 0, stream>>>(featb, wb3, b3, zeros, feat, featb);
  k_conv_mfma<253, 8, 16, 16, 16, 0, false><<<B * H, 256, 0, stream>>>(featb, wb4, b4, zeros, feat, featb);
  k_conv_mfma<269, 9, 2, 16, 0, 0, true><<<B * H, 256, 0, stream>>>(featb, wb5, b5, zeros, out, nullptr);
}

// Round 5
// 247.706 us; speedup vs baseline: 10.7690x; 1.1953x over previous
//
#include <hip/hip_runtime.h>

// ---------------------------------------------------------------------------
// PWC-Net decoder level (B=16, C=48, H=64, W=128) — MFMA implicit-GEMM convs.
// d_out = [flow 16*2*64*128][feat_out 16*269*64*128] (f32)
// Reference out-channel order: [c4 0..15][c3 16..39][c2 40..87][c1 88..135]
//                    [corr 136..216][feat1 217..264][upflow 265..266][upfeat 267..268]
// featb (bf16 [B][H][W][272]) uses a PERMUTED channel order for aligned writes:
//   [c4][c3][c2][c1][f1 136..183][corr 184..264][upflow][upfeat][pad 269..271]
// Permutation baked into weight repack (featb2ref).
// Conv blocks: 2 output rows (M=256), 4 waves x 4 M-frags, K-chunks of 32ch.
// ---------------------------------------------------------------------------

#define DEVFN __device__ __forceinline__

constexpr int B = 16, H = 64, W = 128, HW = H * W;
constexpr int CF = 48;
constexpr int PFC = 217;
constexpr int H2 = 32, W2 = 64, HW2 = H2 * W2;
constexpr int FC = 269;
constexpr int FCP = 272;
constexpr int FLOW_ELEMS = B * 2 * HW;

constexpr int OFF_CORR = 136, OFF_F1 = 217, OFF_UF = 265, OFF_UPFEAT = 267;
constexpr int FB_F1 = 136, FB_CORR = 184;

// ws layout (bytes)
constexpr size_t WS_ZEROS = 0;
constexpr size_t WS_FEATB = 256;
constexpr size_t FEATB_BYTES = (size_t)B * HW * FCP * 2;
constexpr size_t WS_WARPEDH = WS_FEATB + FEATB_BYTES;
constexpr size_t WARPEDH_BYTES = (size_t)3 * B * HW * 16 * 2;
constexpr size_t WS_PART = WS_WARPEDH + WARPEDH_BYTES;
constexpr size_t PART_BYTES = (size_t)7 * B * 2 * HW * 4;
constexpr size_t WS_WB = WS_PART + PART_BYTES;

typedef short bf16x8 __attribute__((ext_vector_type(8)));
typedef float f32x4 __attribute__((ext_vector_type(4)));
typedef _Float16 h16x2 __attribute__((ext_vector_type(2)));
typedef _Float16 h16x8 __attribute__((ext_vector_type(8)));

DEVFN float leaky(float x) { return x >= 0.f ? x : 0.1f * x; }

DEVFN unsigned short f2b(float f) {  // RNE f32 -> bf16
  unsigned int u = __float_as_uint(f);
  u += 0x7FFFu + ((u >> 16) & 1u);
  return (unsigned short)(u >> 16);
}

DEVFN void gload16(const void* g, void* l) {
  __builtin_amdgcn_global_load_lds(
      (const __attribute__((address_space(1))) void*)g,
      (__attribute__((address_space(3))) void*)l, 16, 0, 0);
}

DEVFN int featb2ref(int p) {
  if (p >= FB_F1 && p < FB_CORR) return OFF_F1 + (p - FB_F1);
  if (p >= FB_CORR && p < 265) return OFF_CORR + (p - FB_CORR);
  return p;
}

// ---------------- fused weight repack (all 5 convs) + zeros init -----------
// wb layout per conv: [chunk][tap][co][qpos][j], swizzle baked.
__global__ __launch_bounds__(256) void k_repack_all(
    const float* __restrict__ w1, const float* __restrict__ w2,
    const float* __restrict__ w3, const float* __restrict__ w4,
    const float* __restrict__ w5,
    unsigned short* __restrict__ wb1, unsigned short* __restrict__ wb2,
    unsigned short* __restrict__ wb3, unsigned short* __restrict__ wb4,
    unsigned short* __restrict__ wb5, unsigned short* __restrict__ zeros) {
  int blk = blockIdx.x;
  if (blk == 0 && threadIdx.x < 32) zeros[threadIdx.x] = 0;
  const float* w;
  unsigned short* wb;
  int CIN, COUT, COUTP, IN_OFF, rbase;
  if (blk < 270)       { w = w1; wb = wb1; CIN = 133; COUT = 48; COUTP = 48; IN_OFF = 136; rbase = 0; }
  else if (blk < 594)  { w = w2; wb = wb2; CIN = 181; COUT = 48; COUTP = 48; IN_OFF = 88;  rbase = 270; }
  else if (blk < 882)  { w = w3; wb = wb3; CIN = 229; COUT = 24; COUTP = 32; IN_OFF = 40;  rbase = 594; }
  else if (blk < 1026) { w = w4; wb = wb4; CIN = 253; COUT = 16; COUTP = 16; IN_OFF = 16;  rbase = 882; }
  else                 { w = w5; wb = wb5; CIN = 269; COUT = 2;  COUTP = 16; IN_OFF = 0;   rbase = 1026; }
  int e = (blk - rbase) * 256 + threadIdx.x;
  int nchunk = (CIN + 31) >> 5;
  int TOT = nchunk * 9 * COUTP * 32;
  if (e >= TOT) return;
  int j = e & 7, qpos = (e >> 3) & 3;
  int row = e >> 5;
  int co = row % COUTP;
  int tapch = row / COUTP;
  int tap = tapch % 9, ch = tapch / 9;
  int k = ch * 32 + ((qpos ^ ((co >> 1) & 3)) << 3) + j;
  float v = 0.f;
  if (co < COUT && k < CIN) {
    int ci = featb2ref(IN_OFF + k) - IN_OFF;
    v = w[(co * CIN + ci) * 9 + tap];
  }
  wb[e] = f2b(v);
}

// ------- fused: deconv_feat partials (blk<3584) + deconv_flow (rest) -------
__global__ __launch_bounds__(256) void k_dcf_dflow(
    const float* __restrict__ pfeat, const float* __restrict__ wup,
    const float* __restrict__ pflow, const float* __restrict__ wuf,
    const float* __restrict__ buf_, float* __restrict__ partial,
    float* __restrict__ feat, unsigned short* __restrict__ featb) {
  __shared__ float wl[1024];
  __shared__ float red[2048];
  int tid = threadIdx.x;
  if (blockIdx.x >= 3584) {
    // ---- deconv4x4 s2 on prev_flow ----
    int t = (blockIdx.x - 3584) * 256 + tid;
    if (t >= B * 2 * HW) return;
    int x = t % W, y = (t / W) % H, co = (t / HW) % 2, b = t / (2 * HW);
    float acc = buf_[co];
    int ky0 = ((y & 1) == 0) ? 1 : 0;
    int kx0 = ((x & 1) == 0) ? 1 : 0;
#pragma unroll
    for (int kyi = 0; kyi < 2; ++kyi) {
      int ky = ky0 + 2 * kyi;
      int iy = (y + 1 - ky) >> 1;
      if (iy < 0 || iy >= H2) continue;
#pragma unroll
      for (int kxi = 0; kxi < 2; ++kxi) {
        int kx = kx0 + 2 * kxi;
        int ix = (x + 1 - kx) >> 1;
        if (ix < 0 || ix >= W2) continue;
#pragma unroll
        for (int ci = 0; ci < 2; ++ci)
          acc += pflow[(b * 2 + ci) * HW2 + iy * W2 + ix] *
                 wuf[((ci * 2 + co) * 4 + ky) * 4 + kx];
      }
    }
    int pix = (b * H + y) * W + x;
    feat[(b * FC + OFF_UF + co) * HW + y * W + x] = acc;
    featb[pix * FCP + OFF_UF + co] = f2b(acc);
    if (co == 0) {
      featb[pix * FCP + 269] = 0;
      featb[pix * FCP + 270] = 0;
      featb[pix * FCP + 271] = 0;
    }
    return;
  }
  // ---- deconv4x4 s2 on prev_feat: 32-ch-chunk partials ----
  int blk = blockIdx.x;
  int chunk = blk % 7, t2 = blk / 7;
  int y2 = t2 % H2, b = t2 / H2;
  int ch0 = chunk * 32;
  for (int i = tid; i < 1024; i += 256) {
    int ci = ch0 + (i >> 5);
    wl[i] = (ci < PFC) ? wup[ci * 32 + (i & 31)] : 0.f;
  }
  __syncthreads();
  int x2 = tid & 63, cg = tid >> 6;
  float acc[8];
#pragma unroll
  for (int v = 0; v < 8; ++v) acc[v] = 0.f;
#pragma unroll 1
  for (int k = 0; k < 8; ++k) {
    int cil = cg * 8 + k;
    int ci = ch0 + cil;
    bool cv = ci < PFC;
    const float* src = pfeat + ((size_t)b * PFC + ci) * HW2;
    float iv[3][3];
#pragma unroll
    for (int dy = -1; dy <= 1; ++dy)
#pragma unroll
      for (int dx = -1; dx <= 1; ++dx) {
        int iy = y2 + dy, ix = x2 + dx;
        float v = 0.f;
        if (cv && iy >= 0 && iy < H2 && ix >= 0 && ix < W2) v = src[iy * W2 + ix];
        iv[dy + 1][dx + 1] = v;
      }
    const float* wc = &wl[cil * 32];
#pragma unroll
    for (int co = 0; co < 2; ++co)
#pragma unroll
      for (int ry = 0; ry < 2; ++ry)
#pragma unroll
        for (int rx = 0; rx < 2; ++rx) {
          float s = acc[co * 4 + ry * 2 + rx];
#pragma unroll
          for (int dy = ry - 1; dy <= ry; ++dy) {
            int ky = 1 + ry - 2 * dy;
#pragma unroll
            for (int dx = rx - 1; dx <= rx; ++dx) {
              int kx = 1 + rx - 2 * dx;
              s += iv[dy + 1][dx + 1] * wc[co * 16 + ky * 4 + kx];
            }
          }
          acc[co * 4 + ry * 2 + rx] = s;
        }
  }
#pragma unroll
  for (int v = 0; v < 8; ++v) red[(cg * 64 + x2) * 8 + v] = acc[v];
  __syncthreads();
  for (int idx = tid; idx < 512; idx += 256) {
    int x2b = idx & 63, vi = idx >> 6;
    float s = red[(0 + x2b) * 8 + vi] + red[(64 + x2b) * 8 + vi] +
              red[(128 + x2b) * 8 + vi] + red[(192 + x2b) * 8 + vi];
    int co = vi >> 2, ry = (vi >> 1) & 1, rx = vi & 1;
    partial[(size_t)chunk * (B * 2 * HW) + (size_t)(b * 2 + co) * HW +
            (2 * y2 + ry) * W + (2 * x2b + rx)] = s;
  }
}

// --------- fused: finalize upfeat (blk<1024) + backwarp (rest) -------------
__global__ __launch_bounds__(256) void k_fin_backwarp(
    const float* __restrict__ partial, const float* __restrict__ bup,
    const float* __restrict__ feat2, float* __restrict__ feat,
    unsigned short* __restrict__ featb, unsigned short* __restrict__ warpedh) {
  int tid = threadIdx.x;
  if (blockIdx.x < 1024) {
    int t = blockIdx.x * 256 + tid;
    float s = 0.f;
#pragma unroll
    for (int c = 0; c < 7; ++c) s += partial[(size_t)c * (B * 2 * HW) + t];
    int rem = t % HW;
    int co = (t / HW) & 1;
    int b = t / (2 * HW);
    s += bup[co];
    feat[((size_t)b * FC + OFF_UPFEAT + co) * HW + rem] = s;
    featb[((size_t)(b * H) * W + rem) * FCP + OFF_UPFEAT + co] = f2b(s);
    return;
  }
  int t = (blockIdx.x - 1024) * 256 + tid;
  if (t >= B * HW) return;
  int x = t % W, y = (t / W) % H, b = t / HW;
  const float SX = 1.25f * (float)W / (float)(W - 1);
  const float SY = 1.25f * (float)H / (float)(H - 1);
  float fx = feat[(b * FC + OFF_UF + 0) * HW + y * W + x];
  float fy = feat[(b * FC + OFF_UF + 1) * HW + y * W + x];
  float px = (float)x + fx * SX;
  float py = (float)y + fy * SY;
  float x0f = floorf(px), y0f = floorf(py);
  int ix0 = (int)x0f, iy0 = (int)y0f;
  float wx1 = px - x0f, wx0 = 1.f - wx1;
  float wy1 = py - y0f, wy0 = 1.f - wy1;
  bool vx0 = (ix0 >= 0) & (ix0 < W), vx1 = (ix0 + 1 >= 0) & (ix0 + 1 < W);
  bool vy0 = (iy0 >= 0) & (iy0 < H), vy1 = (iy0 + 1 >= 0) & (iy0 + 1 < H);
  float w00 = (vx0 && vy0) ? wx0 * wy0 : 0.f;
  float w01 = (vx1 && vy0) ? wx1 * wy0 : 0.f;
  float w10 = (vx0 && vy1) ? wx0 * wy1 : 0.f;
  float w11 = (vx1 && vy1) ? wx1 * wy1 : 0.f;
  float wsum = w00 + w01 + w10 + w11;
  float m = wsum > 0.999f ? 1.f : 0.f;
  w00 *= m; w01 *= m; w10 *= m; w11 *= m;
  int cx0 = min(max(ix0, 0), W - 1), cx1 = min(max(ix0 + 1, 0), W - 1);
  int cy0 = min(max(iy0, 0), H - 1), cy1 = min(max(iy0 + 1, 0), H - 1);
  const float* s = feat2 + b * CF * HW;
  int o00 = cy0 * W + cx0, o01 = cy0 * W + cx1, o10 = cy1 * W + cx0, o11 = cy1 * W + cx1;
#pragma unroll 1
  for (int chunk = 0; chunk < 3; ++chunk) {
    h16x8 out0, out1;
#pragma unroll
    for (int k = 0; k < 16; ++k) {
      const float* sc = s + (chunk * 16 + k) * HW;
      float v = w00 * sc[o00] + w01 * sc[o01] + w10 * sc[o10] + w11 * sc[o11];
      if (k < 8) out0[k & 7] = (_Float16)v;
      else       out1[k & 7] = (_Float16)v;
    }
    h16x8* dst = (h16x8*)(warpedh + ((size_t)chunk * B * HW + t) * 16);
    dst[0] = out0;
    dst[1] = out1;
  }
}

// --------------------------- correlation + leaky ---------------------------
__global__ __launch_bounds__(256) void k_corr(const float* __restrict__ f1,
                                              const unsigned short* __restrict__ warpedh,
                                              const unsigned short* __restrict__ zeros,
                                              float* __restrict__ feat,
                                              unsigned short* __restrict__ featb) {
  __shared__ __align__(16) unsigned short lds[5 * 136 * 16];
  const int swz = ((blockIdx.x & 7) << 7) | (blockIdx.x >> 3);
  const int y = swz & 63, b = swz >> 6;
  const int tid = threadIdx.x;
  const int px = tid >> 1, h = tid & 1;
  const int lane = tid & 63, wv = tid >> 6;
  const int pix = (b * H + y) * W + px;
  const h16x8* hp = (const h16x8*)lds;
  char* ldsc = (char*)lds;
  const float inv = 1.f / 48.f;

#pragma unroll 1
  for (int half = 0; half < 2; ++half) {
    const int R = half ? 4 : 5;
    const int dybase = half ? 5 : 0;
    const int ND = R * 9;
    float acc[45];
#pragma unroll
    for (int d = 0; d < 45; ++d) acc[d] = 0.f;
#pragma unroll 1
    for (int chunk = 0; chunk < 3; ++chunk) {
      __syncthreads();
      const int NQ = R * 136 * 2;
      for (int q0 = 0; q0 < NQ; q0 += 256) {
        int q = q0 + tid;
        if (q < NQ) {
          int pr = q >> 1, u = q & 1;
          int r = pr / 136, p = pr - r * 136;
          int sw = (p >> 2) & 1;
          int yy = y + dybase + r - 4, xx = p - 4;
          const unsigned short* src = zeros;
          if (yy >= 0 && yy < H && xx >= 0 && xx < W)
            src = warpedh + (((size_t)chunk * B * H + b * H + yy) * W + xx) * 16 +
                  (u ^ sw) * 8;
          gload16(src, ldsc + (size_t)q0 * 16 + wv * 1024 + lane * 16);
        }
      }
      float av[8];
      const int c0 = chunk * 16 + h * 8;
#pragma unroll
      for (int j = 0; j < 8; ++j)
        av[j] = f1[((size_t)b * CF + c0 + j) * HW + y * W + px];
      h16x2 fh[4];
#pragma unroll
      for (int j = 0; j < 4; ++j) {
        fh[j][0] = (_Float16)av[2 * j];
        fh[j][1] = (_Float16)av[2 * j + 1];
      }
      asm volatile("s_waitcnt vmcnt(0)" ::: "memory");
      __syncthreads();
      if (half == 0) {
#pragma unroll
        for (int j = 0; j < 8; ++j)
          feat[((size_t)b * FC + OFF_F1 + c0 + j) * HW + y * W + px] = av[j];
        uint4 qv;
        qv.x = (unsigned)f2b(av[0]) | ((unsigned)f2b(av[1]) << 16);
        qv.y = (unsigned)f2b(av[2]) | ((unsigned)f2b(av[3]) << 16);
        qv.z = (unsigned)f2b(av[4]) | ((unsigned)f2b(av[5]) << 16);
        qv.w = (unsigned)f2b(av[6]) | ((unsigned)f2b(av[7]) << 16);
        *(uint4*)(featb + (size_t)pix * FCP + FB_F1 + c0) = qv;
      }
#pragma unroll
      for (int dy = 0; dy < 5; ++dy) {
        if (dy < R) {
#pragma unroll
          for (int dx = 0; dx < 9; ++dx) {
            int p = px + dx;
            int sw = (p >> 2) & 1;
            h16x8 v = hp[((dy * 136 + p) << 1) | (h ^ sw)];
            float a = acc[dy * 9 + dx];
            a = __builtin_amdgcn_fdot2((h16x2){v[0], v[1]}, fh[0], a, false);
            a = __builtin_amdgcn_fdot2((h16x2){v[2], v[3]}, fh[1], a, false);
            a = __builtin_amdgcn_fdot2((h16x2){v[4], v[5]}, fh[2], a, false);
            a = __builtin_amdgcn_fdot2((h16x2){v[6], v[7]}, fh[3], a, false);
            acc[dy * 9 + dx] = a;
          }
        }
      }
    }
#pragma unroll
    for (int d = 0; d < 45; ++d) {
      if (d < ND) {
        float s = acc[d] + __shfl_xor(acc[d], 1);
        acc[d] = leaky(s * inv);
      }
    }
    if (h == 0) {
#pragma unroll
      for (int d = 0; d < 45; ++d)
        if (d < ND)
          feat[((size_t)b * FC + OFF_CORR + dybase * 9 + d) * HW + y * W + px] = acc[d];
    } else {
      unsigned short* fb = featb + (size_t)pix * FCP + FB_CORR + dybase * 9;
      if (half == 0) {
#pragma unroll
        for (int g = 0; g < 5; ++g) {
          uint4 qv;
          qv.x = (unsigned)f2b(acc[8 * g + 0]) | ((unsigned)f2b(acc[8 * g + 1]) << 16);
          qv.y = (unsigned)f2b(acc[8 * g + 2]) | ((unsigned)f2b(acc[8 * g + 3]) << 16);
          qv.z = (unsigned)f2b(acc[8 * g + 4]) | ((unsigned)f2b(acc[8 * g + 5]) << 16);
          qv.w = (unsigned)f2b(acc[8 * g + 6]) | ((unsigned)f2b(acc[8 * g + 7]) << 16);
          *(uint4*)(fb + 8 * g) = qv;
        }
#pragma unroll
        for (int d = 40; d < 45; ++d) fb[d] = f2b(acc[d]);
      } else {
        fb[0] = f2b(acc[0]);
        fb[1] = f2b(acc[1]);
        fb[2] = f2b(acc[2]);
#pragma unroll
        for (int g = 0; g < 4; ++g) {
          uint4 qv;
          qv.x = (unsigned)f2b(acc[3 + 8 * g + 0]) | ((unsigned)f2b(acc[3 + 8 * g + 1]) << 16);
          qv.y = (unsigned)f2b(acc[3 + 8 * g + 2]) | ((unsigned)f2b(acc[3 + 8 * g + 3]) << 16);
          qv.z = (unsigned)f2b(acc[3 + 8 * g + 4]) | ((unsigned)f2b(acc[3 + 8 * g + 5]) << 16);
          qv.w = (unsigned)f2b(acc[3 + 8 * g + 6]) | ((unsigned)f2b(acc[3 + 8 * g + 7]) << 16);
          *(uint4*)(fb + 3 + 8 * g) = qv;
        }
        fb[35] = f2b(acc[35]);
      }
    }
  }
}

// --------------------- conv3x3 + bias + leaky via MFMA ---------------------
// Block = 2 output rows (M=256). 4 waves: wave wv -> out-row wr=wv>>1,
// x-half wc=wv&1 (4 M-frags of 16 px). Stages 4 input rows + weight slab
// per 32-ch chunk.
template <int CIN, int NCHUNK, int COUT, int COUTP, int IN_OFF, int OUT_OFF, bool TO_FLOW>
__global__ __launch_bounds__(256) void k_conv_mfma(
    const unsigned short* __restrict__ featb, const unsigned short* __restrict__ wb,
    const float* __restrict__ bias, const unsigned short* __restrict__ zeros,
    float* __restrict__ fout, unsigned short* __restrict__ bout) {
  constexpr int NF = COUTP / 16;
  constexpr int ROWPX = 144;
  constexpr int IN_ELE = 4 * ROWPX * 32;      // ushorts
  constexpr int W_SLAB = 9 * COUTP * 32;      // ushorts per chunk
  constexpr int NWI = (W_SLAB * 2) / 1024;    // weight gloads per chunk
  constexpr int CLIM = 264 - IN_OFF;

  __shared__ unsigned short lds[IN_ELE + W_SLAB];

  const int swz = ((blockIdx.x & 7) << 6) | (blockIdx.x >> 3);  // 512 blocks
  const int y0 = (swz & 31) * 2, b = swz >> 5;
  const int lane = threadIdx.x & 63, wv = threadIdx.x >> 6;
  const int wr = wv >> 1, wc = wv & 1;
  const int arow = lane & 15, aslc = lane >> 4;

  // input staging descriptors: 9 per wave (i = wv + t*4, 36 total)
  const unsigned short* gp[9];
  int c8a[9];
  int lofs[9];
#pragma unroll
  for (int t = 0; t < 9; ++t) {
    int i = wv + t * 4;
    int r = i / 9, seg = i - r * 9;
    int slot = seg * 16 + (lane >> 2);
    int sub8 = ((lane & 3) ^ ((slot >> 1) & 3)) << 3;
    int yy = y0 + r - 1, xx = slot - 1;
    lofs[t] = (r * ROWPX + seg * 16) * 64;
    gp[t] = zeros; c8a[t] = 1 << 20;
    if (yy >= 0 && yy < H && xx >= 0 && xx < W) {
      gp[t] = featb + ((b * H + yy) * W + xx) * FCP + IN_OFF + sub8;
      c8a[t] = sub8;
    }
  }

  int a_off[4][3];
#pragma unroll
  for (int mi = 0; mi < 4; ++mi)
#pragma unroll
    for (int kx = 0; kx < 3; ++kx) {
      int slot = (wc * 4 + mi) * 16 + arow + kx;
      a_off[mi][kx] = slot * 32 + ((aslc ^ ((slot >> 1) & 3)) << 3);
    }
  int b_off[NF];
#pragma unroll
  for (int nf = 0; nf < NF; ++nf) {
    int co = nf * 16 + arow;
    b_off[nf] = IN_ELE + co * 32 + ((aslc ^ ((co >> 1) & 3)) << 3);
  }

  f32x4 acc[4][NF];
#pragma unroll
  for (int mi = 0; mi < 4; ++mi)
#pragma unroll
    for (int nf = 0; nf < NF; ++nf) acc[mi][nf] = (f32x4){0.f, 0.f, 0.f, 0.f};

  char* ldsc = (char*)lds;

  for (int ch = 0; ch < NCHUNK; ++ch) {
    const int ci0 = ch * 32;
    __syncthreads();
#pragma unroll
    for (int t = 0; t < 9; ++t) {
      const unsigned short* g = (c8a[t] + ci0 <= CLIM) ? gp[t] + ci0 : zeros;
      gload16(g, ldsc + lofs[t]);
    }
    for (int wi = wv; wi < NWI; wi += 4)
      gload16(wb + (size_t)ch * W_SLAB + wi * 512 + lane * 8,
              ldsc + IN_ELE * 2 + wi * 1024);
    asm volatile("s_waitcnt vmcnt(0)" ::: "memory");
    __syncthreads();
#pragma unroll
    for (int ky = 0; ky < 3; ++ky) {
#pragma unroll
      for (int kx = 0; kx < 3; ++kx) {
        bf16x8 afr[4];
#pragma unroll
        for (int mi = 0; mi < 4; ++mi)
          afr[mi] = *(const bf16x8*)(lds + a_off[mi][kx] + (wr + ky) * (ROWPX * 32));
#pragma unroll
        for (int nf = 0; nf < NF; ++nf) {
          bf16x8 bfr = *(const bf16x8*)(lds + b_off[nf] + (ky * 3 + kx) * (COUTP * 32));
#pragma unroll
          for (int mi = 0; mi < 4; ++mi)
            acc[mi][nf] = __builtin_amdgcn_mfma_f32_16x16x32_bf16(
                afr[mi], bfr, acc[mi][nf], 0, 0, 0);
        }
      }
    }
  }

  const int dcol = lane & 15;
  const int yout = y0 + wr;
#pragma unroll
  for (int nf = 0; nf < NF; ++nf) {
    int co = nf * 16 + dcol;
    if (co < COUT) {
      float bv = bias[co];
#pragma unroll
      for (int mi = 0; mi < 4; ++mi) {
#pragma unroll
        for (int r = 0; r < 4; ++r) {
          int pixel = (wc * 4 + mi) * 16 + (lane >> 4) * 4 + r;
          float v = leaky(acc[mi][nf][r] + bv);
          if constexpr (TO_FLOW) {
            fout[(b * 2 + co) * HW + yout * W + pixel] = v;
          } else {
            fout[(b * FC + OUT_OFF + co) * HW + yout * W + pixel] = v;
            bout[((b * H + yout) * W + pixel) * FCP + OUT_OFF + co] = f2b(v);
          }
        }
      }
    }
  }
}

// ---------------------------------------------------------------------------
extern "C" void kernel_launch(void* const* d_in, const int* in_sizes, int n_in,
                              void* d_out, int out_size, void* d_ws, size_t ws_size,
                              hipStream_t stream) {
  (void)in_sizes; (void)n_in; (void)out_size; (void)ws_size;
  const float* feat_1 = (const float*)d_in[0];
  const float* feat_2 = (const float*)d_in[1];
  const float* prev_flow = (const float*)d_in[2];
  const float* prev_feat = (const float*)d_in[3];
  const float* w1 = (const float*)d_in[4];
  const float* b1 = (const float*)d_in[5];
  const float* w2 = (const float*)d_in[6];
  const float* b2 = (const float*)d_in[7];
  const float* w3 = (const float*)d_in[8];
  const float* b3 = (const float*)d_in[9];
  const float* w4 = (const float*)d_in[10];
  const float* b4 = (const float*)d_in[11];
  const float* w5 = (const float*)d_in[12];
  const float* b5 = (const float*)d_in[13];
  const float* w_upflow = (const float*)d_in[14];
  const float* b_upflow = (const float*)d_in[15];
  const float* w_upfeat = (const float*)d_in[16];
  const float* b_upfeat = (const float*)d_in[17];

  float* out = (float*)d_out;
  float* feat = out + FLOW_ELEMS;

  char* ws = (char*)d_ws;
  unsigned short* zeros = (unsigned short*)(ws + WS_ZEROS);
  unsigned short* featb = (unsigned short*)(ws + WS_FEATB);
  unsigned short* warpedh = (unsigned short*)(ws + WS_WARPEDH);
  float* partial = (float*)(ws + WS_PART);
  unsigned short* wb1 = (unsigned short*)(ws + WS_WB);
  unsigned short* wb2 = wb1 + 5 * 9 * 48 * 32;
  unsigned short* wb3 = wb2 + 6 * 9 * 48 * 32;
  unsigned short* wb4 = wb3 + 8 * 9 * 32 * 32;
  unsigned short* wb5 = wb4 + 8 * 9 * 16 * 32;

  k_repack_all<<<1188, 256, 0, stream>>>(w1, w2, w3, w4, w5,
                                         wb1, wb2, wb3, wb4, wb5, zeros);
  k_dcf_dflow<<<3584 + 1024, 256, 0, stream>>>(prev_feat, w_upfeat, prev_flow,
                                               w_upflow, b_upflow, partial, feat, featb);
  k_fin_backwarp<<<1024 + 512, 256, 0, stream>>>(partial, b_upfeat, feat_2,
                                                 feat, featb, warpedh);
  k_corr<<<B * H, 256, 0, stream>>>(feat_1, warpedh, zeros, feat, featb);

  k_conv_mfma<133, 5, 48, 48, 136, 88, false><<<B * H / 2, 256, 0, stream>>>(featb, wb1, b1, zeros, feat, featb);
  k_conv_mfma<181, 6, 48, 48, 88, 40, false><<<B * H / 2, 256, 0, stream>>>(featb, wb2, b2, zeros, feat, featb);
  k_conv_mfma<229, 8, 24, 32, 40, 16, false><<<B * H / 2, 256, 0, stream>>>(featb, wb3, b3, zeros, feat, featb);
  k_conv_mfma<253, 8, 16, 16, 16, 0, false><<<B * H / 2, 256, 0, stream>>>(featb, wb4, b4, zeros, feat, featb);
  k_conv_mfma<269, 9, 2, 16, 0, 0, true><<<B * H / 2, 256, 0, stream>>>(featb, wb5, b5, zeros, out, nullptr);
}